// Round 8
// baseline (279.706 us; speedup 1.0000x reference)
//
#include <hip/hip_runtime.h>
#include <math.h>

#define BATCH 2
#define SEQ   2048
#define NH    32
#define HID   2048
#define CHUNK 256
#define NCH   8
#define NBCH  (BATCH*NCH*NH)   // 512
#define PST   72               // padded bf16 LDS leading dim (b128-alignable)
#define BK    256
#define APST  264              // BK+8 shorts; row stride 528 B = 33*16 (b128-aligned)
#define KSPLIT 4
#define KSEG  (HID / KSPLIT)   // 512

typedef __attribute__((ext_vector_type(4))) float f32x4;
typedef __attribute__((ext_vector_type(8))) short bf16x8;
typedef unsigned int uint;
typedef unsigned short ushort;

__device__ __forceinline__ float softplusf(float x) {
    return x > 20.f ? x : log1pf(expf(x));
}

__device__ __forceinline__ short f2bf(float f) {
    union { float f; uint u; } v; v.f = f;
    uint r = v.u + 0x7FFF + ((v.u >> 16) & 1);
    return (short)(r >> 16);
}
__device__ __forceinline__ float bf2f(ushort s) {
    union { uint u; float f; } v; v.u = ((uint)s) << 16; return v.f;
}
__device__ __forceinline__ uint packbf2(float lo, float hi) {
    return (uint)(ushort)f2bf(lo) | ((uint)(ushort)f2bf(hi) << 16);
}

struct BF8 { union { bf16x8 v; short s[8]; }; };

__device__ __forceinline__ bf16x8 load_cvt8(const float* p, float scale) {
    float4 a = *(const float4*)p;
    float4 b = *(const float4*)(p + 4);
    BF8 r;
    r.s[0]=f2bf(a.x*scale); r.s[1]=f2bf(a.y*scale); r.s[2]=f2bf(a.z*scale); r.s[3]=f2bf(a.w*scale);
    r.s[4]=f2bf(b.x*scale); r.s[5]=f2bf(b.y*scale); r.s[6]=f2bf(b.z*scale); r.s[7]=f2bf(b.w*scale);
    return r.v;
}

__device__ __forceinline__ bf16x8 cvt8(float4 a, float4 b, float s) {
    BF8 r;
    r.s[0]=f2bf(a.x*s); r.s[1]=f2bf(a.y*s); r.s[2]=f2bf(a.z*s); r.s[3]=f2bf(a.w*s);
    r.s[4]=f2bf(b.x*s); r.s[5]=f2bf(b.y*s); r.s[6]=f2bf(b.z*s); r.s[7]=f2bf(b.w*s);
    return r.v;
}

#define MFMA(a,b,c) __builtin_amdgcn_mfma_f32_16x16x32_bf16((a),(b),(c),0,0,0)

// ---------------------------------------------------------------------------
// K1: dt/g projections as bf16 MFMA GEMM (split-K by 4), plus 32 trailing
// blocks that build nwWT[h][q][p] = bf16(o_w[h][p][q] * norm_w[h*64+p]).
// ---------------------------------------------------------------------------
__global__ __launch_bounds__(256) void k_proj(
    const float* __restrict__ hs_ab, const float* __restrict__ hs_g,
    const float* __restrict__ dt_w, const float* __restrict__ g_w,
    const float* __restrict__ o_w,  const float* __restrict__ norm_w,
    float* __restrict__ part, short* __restrict__ nwWT)
{
    __shared__ __align__(16) short As[32 * APST];
    __shared__ __align__(16) short Bs[32 * APST];
    int blk = blockIdx.x;
    int t = threadIdx.x;

    if (blk >= 2 * KSPLIT * 128) {
        // --- weight prep: transpose o_w per head, fold norm_w, cast bf16 ---
        int h = blk - 2 * KSPLIT * 128;
        float* tile = (float*)As;   // 64x64 f32 = 16 KB
        {
            int p = t >> 2, q0 = (t & 3) * 16;
            const float* wp = o_w + (size_t)h * 4096 + p * 64 + q0;
            #pragma unroll
            for (int i = 0; i < 4; ++i)
                *(float4*)(tile + p * 64 + q0 + i * 4) = *(const float4*)(wp + i * 4);
        }
        __syncthreads();
        int q = t >> 2, p0 = (t & 3) * 16;
        uint us[8];
        #pragma unroll
        for (int j = 0; j < 8; ++j) {
            float lo = tile[(p0 + 2*j    ) * 64 + q] * norm_w[h * 64 + p0 + 2*j];
            float hi = tile[(p0 + 2*j + 1) * 64 + q] * norm_w[h * 64 + p0 + 2*j + 1];
            us[j] = packbf2(lo, hi);
        }
        uint* dst = (uint*)(nwWT + (size_t)h * 4096 + q * 64 + p0);
        *(uint4*)dst       = make_uint4(us[0], us[1], us[2], us[3]);
        *(uint4*)(dst + 4) = make_uint4(us[4], us[5], us[6], us[7]);
        return;
    }

    int ksp = blk >> 8;          // 0..3 : K segment
    int rem = blk & 255;
    int which = rem >> 7;        // 0..1 : ab vs g
    int rt = rem & 127;          // 0..127 : 32-row tile
    int r0 = rt * 32;
    const float* Am = which ? hs_g : hs_ab;
    const float* W  = which ? g_w  : dt_w;
    int w = t >> 6, lane = t & 63, quad = lane >> 4, l16 = lane & 15;
    int mh = w & 1, nh = w >> 1;

    f32x4 acc = (f32x4){0.f, 0.f, 0.f, 0.f};

    for (int kc = ksp * KSEG; kc < ksp * KSEG + KSEG; kc += BK) {
        __syncthreads();
        {   // stage A: 32 rows x BK cols, bf16-packed
            int row = t >> 3, k0 = (t & 7) * 32;
            const float* src = Am + (size_t)(r0 + row) * HID + kc + k0;
            uint* dst = (uint*)(As + row * APST + k0);
            #pragma unroll
            for (int i = 0; i < 4; ++i) {
                float4 a = *(const float4*)(src + i * 8);
                float4 b = *(const float4*)(src + i * 8 + 4);
                dst[i*4+0] = packbf2(a.x, a.y); dst[i*4+1] = packbf2(a.z, a.w);
                dst[i*4+2] = packbf2(b.x, b.y); dst[i*4+3] = packbf2(b.z, b.w);
            }
        }
        if (t < 128) {   // stage W transposed: Bs[n][k] = W[kc+k][n], pair-packed
            int k2 = t * 2;
            const float* w0 = W + (size_t)(kc + k2) * NH;
            const float* w1 = w0 + NH;
            #pragma unroll
            for (int n = 0; n < 32; n += 4) {
                float4 a = *(const float4*)(w0 + n);
                float4 b = *(const float4*)(w1 + n);
                *((uint*)(Bs + (n+0) * APST + k2)) = packbf2(a.x, b.x);
                *((uint*)(Bs + (n+1) * APST + k2)) = packbf2(a.y, b.y);
                *((uint*)(Bs + (n+2) * APST + k2)) = packbf2(a.z, b.z);
                *((uint*)(Bs + (n+3) * APST + k2)) = packbf2(a.w, b.w);
            }
        }
        __syncthreads();
        #pragma unroll
        for (int ks = 0; ks < BK / 32; ++ks) {
            bf16x8 af = *(const bf16x8*)(As + (mh*16 + l16) * APST + ks*32 + quad*8);
            bf16x8 bf = *(const bf16x8*)(Bs + (nh*16 + l16) * APST + ks*32 + quad*8);
            acc = MFMA(af, bf, acc);
        }
    }

    int n = nh * 16 + l16;
    int Rb = r0 + mh * 16 + quad * 4;
    float* pd = part + ((size_t)(which * KSPLIT + ksp) * 4096 + Rb) * 32 + n;
    #pragma unroll
    for (int r = 0; r < 4; ++r)
        pd[r * 32] = acc[r];
}

// ---------------------------------------------------------------------------
// K2: per (b,c,h): sum dt split-K partials + bias + softplus, wave-shfl scan
// of dt*A; emits chunk-ordered cum/dt/w and chunk decay.
// ---------------------------------------------------------------------------
__global__ __launch_bounds__(256) void k_cumsum(
    const float* __restrict__ part, const float* __restrict__ dt_b,
    const float* __restrict__ dt_bias, const float* __restrict__ A_log,
    float* __restrict__ cumc, float* __restrict__ wvc,
    float* __restrict__ dtc, float* __restrict__ cd)
{
    __shared__ float wsum[4];
    int bch = blockIdx.x;
    int h = bch & 31, c = (bch >> 5) & 7, b = bch >> 8;
    int t = threadIdx.x;
    int w = t >> 6, lane = t & 63;
    int rid = (b * SEQ + c * CHUNK + t) * 32 + h;
    float s = part[rid] + part[131072 + rid] + part[262144 + rid] + part[393216 + rid];
    float dt_l = softplusf(s + dt_b[h] + dt_bias[h]);
    float A = -expf(A_log[h]);
    float v = dt_l * A;
    #pragma unroll
    for (int off = 1; off < 64; off <<= 1) {
        float u = __shfl_up(v, off);
        if (lane >= off) v += u;
    }
    if (lane == 63) wsum[w] = v;
    __syncthreads();
    float pre = 0.f;
    #pragma unroll
    for (int i = 0; i < 3; ++i)
        if (i < w) pre += wsum[i];
    float cum = v + pre;
    float tot = wsum[0] + wsum[1] + wsum[2] + wsum[3];
    size_t o = (size_t)bch * CHUNK + t;
    cumc[o] = cum;
    wvc[o] = expf(tot - cum) * dt_l;
    dtc[o] = dt_l;
    if (t == 255) cd[bch] = expf(tot);
}

// ---------------------------------------------------------------------------
// K4: partial chunk states (invB computed inline)
// ---------------------------------------------------------------------------
__global__ __launch_bounds__(256) void k_states(
    const float* __restrict__ kst, const float* __restrict__ vst,
    const float* __restrict__ wvc, float* __restrict__ sp)
{
    __shared__ __align__(16) float kS[64 * 64];
    __shared__ __align__(16) float xS[64 * 64];
    int blk = blockIdx.x;
    int half = blk & 1, bch = blk >> 1;
    int h = bch & 31, c = (bch >> 5) & 7, b = bch >> 8;
    int t = threadIdx.x;
    size_t rowbase = (size_t)b * SEQ + c * CHUNK + half * 128;
    int pg = (t & 15) * 4, ng = (t >> 4) * 4;
    float acc[4][4];
    #pragma unroll
    for (int i = 0; i < 4; ++i)
        #pragma unroll
        for (int j = 0; j < 4; ++j) acc[i][j] = 0.f;

    for (int tt = 0; tt < 2; ++tt) {
        int r0 = t >> 4;
        int c4 = (t & 15) * 4;
        #pragma unroll
        for (int i = 0; i < 4; ++i) {
            int row = r0 + i * 16;
            size_t grow = (rowbase + tt * 64 + row) * NH + h;
            float wv = wvc[(size_t)bch * CHUNK + half * 128 + tt * 64 + row];
            float4 kv = *(const float4*)(kst + grow * 64 + c4);
            float4 xv = *(const float4*)(vst + grow * 64 + c4);
            float ssq = kv.x*kv.x + kv.y*kv.y + kv.z*kv.z + kv.w*kv.w;
            ssq += __shfl_xor(ssq, 1); ssq += __shfl_xor(ssq, 2);
            ssq += __shfl_xor(ssq, 4); ssq += __shfl_xor(ssq, 8);
            float ib = 1.f / fmaxf(sqrtf(ssq), 1e-12f);
            *(float4*)(kS + row * 64 + c4) =
                make_float4(kv.x * ib, kv.y * ib, kv.z * ib, kv.w * ib);
            *(float4*)(xS + row * 64 + c4) =
                make_float4(xv.x * wv, xv.y * wv, xv.z * wv, xv.w * wv);
        }
        __syncthreads();
        for (int ll = 0; ll < 64; ++ll) {
            float4 x4 = *(const float4*)(xS + ll * 64 + pg);
            float4 k4 = *(const float4*)(kS + ll * 64 + ng);
            acc[0][0] += x4.x * k4.x; acc[0][1] += x4.x * k4.y;
            acc[0][2] += x4.x * k4.z; acc[0][3] += x4.x * k4.w;
            acc[1][0] += x4.y * k4.x; acc[1][1] += x4.y * k4.y;
            acc[1][2] += x4.y * k4.z; acc[1][3] += x4.y * k4.w;
            acc[2][0] += x4.z * k4.x; acc[2][1] += x4.z * k4.y;
            acc[2][2] += x4.z * k4.z; acc[2][3] += x4.z * k4.w;
            acc[3][0] += x4.w * k4.x; acc[3][1] += x4.w * k4.y;
            acc[3][2] += x4.w * k4.z; acc[3][3] += x4.w * k4.w;
        }
        __syncthreads();
    }
    size_t obase = (size_t)blk * 4096;
    #pragma unroll
    for (int i = 0; i < 4; ++i)
        *(float4*)(sp + obase + (pg + i) * 64 + ng) =
            make_float4(acc[i][0], acc[i][1], acc[i][2], acc[i][3]);
}

// ---------------------------------------------------------------------------
// K5: inter-chunk scan
// ---------------------------------------------------------------------------
__global__ __launch_bounds__(256) void k_scan(
    const float* __restrict__ sp, const float* __restrict__ cd,
    float* __restrict__ Hp)
{
    size_t id = (size_t)blockIdx.x * 256 + threadIdx.x;
    size_t bh = id >> 12, pn = id & 4095;
    size_t b = bh >> 5, h = bh & 31;
    float carry = 0.f;
    for (int c = 0; c < NCH; ++c) {
        size_t bch = (b * NCH + c) * NH + h;
        float st = sp[(bch * 2) * 4096 + pn] + sp[(bch * 2 + 1) * 4096 + pn];
        Hp[bch * 4096 + pn] = carry;
        carry = cd[bch] * carry + st;
    }
}

// ---------------------------------------------------------------------------
// K6: MFMA intra-chunk + H_prev. R8: 512-thread blocks, one strip per wave.
// Lesson from R4/R6/R7: k_intra time tracks STAGING count (R4 4 stagings
// 40us, R6 6 -> 46, R7 8 -> 61); duplicating staging across blocks is
// strictly negative. This version keeps staging at R4's total (4 tiles per
// chunk, one block per chunk) but runs 8 waves/block (one 32-row strip per
// wave): per-thread staging halves, waves/CU goes 8 -> 16 (2 blocks/CU,
// LDS 56 KB), no inter-block imbalance.
// ---------------------------------------------------------------------------
__global__ __launch_bounds__(512, 2) void k_intra(
    const float* __restrict__ qst, const float* __restrict__ kst,
    const float* __restrict__ vst,
    const float* __restrict__ cumc, const float* __restrict__ dtc,
    const float* __restrict__ Hp,
    short* __restrict__ ygb)
{
    __shared__ __align__(16) short B_s[64 * PST];
    __shared__ __align__(16) short XT_s[64 * PST];
    __shared__ __align__(16) short P_s[8 * 32 * PST];
    __shared__ float sCum[256];
    __shared__ float sDt[256];

    int bch = blockIdx.x;
    int h = bch & 31, c = (bch >> 5) & 7, b = bch >> 8;
    int t = threadIdx.x;
    int w = t >> 6, lane = t & 63;
    int quad = lane >> 4, l16 = lane & 15;
    int strip = w;                          // one strip per wave
    size_t rowbase = (size_t)b * SEQ + c * CHUNK;

    if (t < 256) {
        sCum[t] = cumc[(size_t)bch * CHUNK + t];
        sDt[t]  = dtc[(size_t)bch * CHUNK + t];
    }

    // staging thread mapping (512 threads; constant across st)
    int rowK = t >> 3, c8 = (t & 7) * 8;       // B_s: row, 8-col group
    int ss2 = t & 31, pg4 = (t >> 5) * 4;      // XT: s-pair ss2, 4 p's

    // Q fragments for this wave's strip (l2-normalized)
    bf16x8 cf[2][2];
    #pragma unroll
    for (int lt = 0; lt < 2; ++lt) {
        int l = strip * 32 + lt * 16 + l16;
        size_t grow = (rowbase + l) * NH + h;
        const float* qp = qst + grow * 64 + quad * 8;
        float4 a  = *(const float4*)qp;
        float4 bq = *(const float4*)(qp + 4);
        float4 c2 = *(const float4*)(qp + 32);
        float4 d  = *(const float4*)(qp + 36);
        float ssq = a.x*a.x + a.y*a.y + a.z*a.z + a.w*a.w
                  + bq.x*bq.x + bq.y*bq.y + bq.z*bq.z + bq.w*bq.w
                  + c2.x*c2.x + c2.y*c2.y + c2.z*c2.z + c2.w*c2.w
                  + d.x*d.x + d.y*d.y + d.z*d.z + d.w*d.w;
        ssq += __shfl_xor(ssq, 16);
        ssq += __shfl_xor(ssq, 32);
        float ic = 1.f / fmaxf(sqrtf(ssq), 1e-12f);
        cf[lt][0] = cvt8(a, bq, ic);
        cf[lt][1] = cvt8(c2, d, ic);
    }

    f32x4 acc[2][4];
    #pragma unroll
    for (int lt = 0; lt < 2; ++lt)
        #pragma unroll
        for (int pt = 0; pt < 4; ++pt)
            acc[lt][pt] = (f32x4){0.f, 0.f, 0.f, 0.f};

    {   // H_prev contribution
        bf16x8 hf[4][2];
        #pragma unroll
        for (int pt = 0; pt < 4; ++pt) {
            const float* hp = Hp + (size_t)bch * 4096 + (pt * 16 + l16) * 64 + quad * 8;
            hf[pt][0] = load_cvt8(hp, 1.f);
            hf[pt][1] = load_cvt8(hp + 32, 1.f);
        }
        #pragma unroll
        for (int lt = 0; lt < 2; ++lt)
            #pragma unroll
            for (int pt = 0; pt < 4; ++pt) {
                acc[lt][pt] = MFMA(cf[lt][0], hf[pt][0], acc[lt][pt]);
                acc[lt][pt] = MFMA(cf[lt][1], hf[pt][1], acc[lt][pt]);
            }
    }
    __syncthreads();   // sCum/sDt now visible to all waves
    #pragma unroll
    for (int lt = 0; lt < 2; ++lt) {
        float e[4];
        #pragma unroll
        for (int r = 0; r < 4; ++r)
            e[r] = __expf(sCum[strip * 32 + lt * 16 + quad * 4 + r]);
        #pragma unroll
        for (int pt = 0; pt < 4; ++pt)
            #pragma unroll
            for (int r = 0; r < 4; ++r)
                acc[lt][pt][r] *= e[r];
    }

    short* Pw = P_s + w * 32 * PST;

    for (int st = 0; st < 4; ++st) {
        {   // stage K-hat (bf16): 8 floats per thread, 8-lane row reduce
            size_t gK = (rowbase + st * 64 + rowK) * NH + h;
            const float4* kp = (const float4*)(kst + gK * 64 + c8);
            float4 kv0 = kp[0], kv1 = kp[1];
            float ssq = kv0.x*kv0.x + kv0.y*kv0.y + kv0.z*kv0.z + kv0.w*kv0.w
                      + kv1.x*kv1.x + kv1.y*kv1.y + kv1.z*kv1.z + kv1.w*kv1.w;
            ssq += __shfl_xor(ssq, 1);
            ssq += __shfl_xor(ssq, 2);
            ssq += __shfl_xor(ssq, 4);
            float ib = 1.f / fmaxf(sqrtf(ssq), 1e-12f);
            uint u0 = packbf2(kv0.x * ib, kv0.y * ib);
            uint u1 = packbf2(kv0.z * ib, kv0.w * ib);
            uint u2 = packbf2(kv1.x * ib, kv1.y * ib);
            uint u3 = packbf2(kv1.z * ib, kv1.w * ib);
            *(uint4*)((uint*)(B_s + rowK * PST + c8)) = make_uint4(u0, u1, u2, u3);
        }
        {   // stage dt-scaled X^T: s-pair x 4 p's per thread
            size_t g0 = (rowbase + st * 64 + 2 * ss2) * NH + h;
            float4 xa = *(const float4*)(vst + g0 * 64 + pg4);
            float4 xb = *(const float4*)(vst + (g0 + NH) * 64 + pg4);
            float dt0 = sDt[st * 64 + 2 * ss2];
            float dt1 = sDt[st * 64 + 2 * ss2 + 1];
            uint* xt = (uint*)XT_s;
            xt[(pg4 + 0) * (PST / 2) + ss2] = packbf2(xa.x * dt0, xb.x * dt1);
            xt[(pg4 + 1) * (PST / 2) + ss2] = packbf2(xa.y * dt0, xb.y * dt1);
            xt[(pg4 + 2) * (PST / 2) + ss2] = packbf2(xa.z * dt0, xb.z * dt1);
            xt[(pg4 + 3) * (PST / 2) + ss2] = packbf2(xa.w * dt0, xb.w * dt1);
        }
        __syncthreads();   // staged tile visible

        if (strip * 32 + 31 >= st * 64) {   // wave has causal work this st
            bf16x8 xf[4][2];
            #pragma unroll
            for (int pt = 0; pt < 4; ++pt) {
                #pragma unroll
                for (int ks = 0; ks < 2; ++ks)
                    xf[pt][ks] = *(const bf16x8*)(XT_s + (pt * 16 + l16) * PST + ks * 32 + quad * 8);
            }

            #pragma unroll
            for (int lt = 0; lt < 2; ++lt) {
                int Lt = strip * 32 + lt * 16;
                float cl = sCum[Lt + l16];
                int lrow = lt * 16 + l16;
                #pragma unroll
                for (int mt = 0; mt < 4; ++mt) {
                    int S0 = st * 64 + mt * 16;
                    uint* pdst = (uint*)(Pw + lrow * PST + mt * 16 + quad * 4);
                    if (S0 > Lt + 15) {
                        *(uint2*)pdst = make_uint2(0u, 0u);
                        continue;
                    }
                    f32x4 sa = (f32x4){0.f, 0.f, 0.f, 0.f};
                    bf16x8 af0 = *(const bf16x8*)(B_s + (mt * 16 + l16) * PST + quad * 8);
                    bf16x8 af1 = *(const bf16x8*)(B_s + (mt * 16 + l16) * PST + 32 + quad * 8);
                    sa = MFMA(af0, cf[lt][0], sa);
                    sa = MFMA(af1, cf[lt][1], sa);
                    float vals[4];
                    #pragma unroll
                    for (int r = 0; r < 4; ++r) {
                        int s = S0 + quad * 4 + r;
                        float v = sa[r] * __expf(cl - sCum[s]);
                        vals[r] = (Lt + l16 >= s) ? v : 0.f;
                    }
                    *(uint2*)pdst = make_uint2(packbf2(vals[0], vals[1]),
                                               packbf2(vals[2], vals[3]));
                }
            }
            #pragma unroll
            for (int lt = 0; lt < 2; ++lt) {
                int Lmax = strip * 32 + lt * 16 + 15;
                #pragma unroll
                for (int ks = 0; ks < 2; ++ks) {
                    if (st * 64 + ks * 32 > Lmax) continue;
                    bf16x8 af = *(const bf16x8*)(Pw + (lt * 16 + l16) * PST + ks * 32 + quad * 8);
                    #pragma unroll
                    for (int pt = 0; pt < 4; ++pt)
                        acc[lt][pt] = MFMA(af, xf[pt][ks], acc[lt][pt]);
                }
            }
        }
        __syncthreads();   // all reads done before next st's staging writes
    }

    #pragma unroll
    for (int lt = 0; lt < 2; ++lt)
        #pragma unroll
        for (int pt = 0; pt < 4; ++pt)
            #pragma unroll
            for (int r = 0; r < 4; ++r) {
                int l = strip * 32 + lt * 16 + quad * 4 + r;
                int p = pt * 16 + l16;
                ygb[((rowbase + l) * NH + h) * 64 + p] = f2bf(acc[lt][pt][r]);
            }
}

// ---------------------------------------------------------------------------
// K7: fused gate + RMSNorm + per-head o_proj.
// ---------------------------------------------------------------------------
__global__ __launch_bounds__(256) void k_out(
    const short* __restrict__ ygb, const float* __restrict__ part,
    const float* __restrict__ g_b, const short* __restrict__ nwWT,
    const float* __restrict__ o_b, float* __restrict__ out)
{
    __shared__ __align__(16) short yS[16 * 1024];   // 16 rows x own head-half
    __shared__ float silS[16 * 32];
    __shared__ float scaleS[16];
    int blk = blockIdx.x;
    int half = blk & 1, rt = blk >> 1;
    int r0 = rt * 16;
    int t = threadIdx.x;
    int w = t >> 6, lane = t & 63, quad = lane >> 4, l16 = lane & 15;

    // phase 0: gates (sum g split-K partials + bias, silu) for all 32 heads
    const float* gpart = part + 4 * 131072;
    #pragma unroll
    for (int ii = 0; ii < 2; ++ii) {
        int idx = t + ii * 256;                 // (row 0..15, h 0..31)
        int rr = idx >> 5, hh = idx & 31;
        int rid = (r0 + rr) * 32 + hh;
        float g = gpart[rid] + gpart[131072 + rid] + gpart[262144 + rid]
                + gpart[393216 + rid] + g_b[hh];
        silS[idx] = g / (1.f + expf(-g));
    }
    __syncthreads();

    // phase 1: stream full rows, gated sumsq; stash own half to LDS (swizzled)
    int r = t >> 4, cl = t & 15;
    const char* yrow = (const char*)(ygb + (size_t)(r0 + r) * 2048);
    float ssq = 0.f;
    #pragma unroll
    for (int i = 0; i < 16; ++i) {
        int cb = i * 256 + cl * 16;             // byte offset 0..4095
        uint4 u = *(const uint4*)(yrow + cb);
        float s = silS[r * 32 + (cb >> 7)];
        float v0 = bf2f((ushort)(u.x & 0xFFFF)) * s, v1 = bf2f((ushort)(u.x >> 16)) * s;
        float v2 = bf2f((ushort)(u.y & 0xFFFF)) * s, v3 = bf2f((ushort)(u.y >> 16)) * s;
        float v4 = bf2f((ushort)(u.z & 0xFFFF)) * s, v5 = bf2f((ushort)(u.z >> 16)) * s;
        float v6 = bf2f((ushort)(u.w & 0xFFFF)) * s, v7 = bf2f((ushort)(u.w >> 16)) * s;
        ssq += v0*v0 + v1*v1 + v2*v2 + v3*v3 + v4*v4 + v5*v5 + v6*v6 + v7*v7;
        if ((cb >> 11) == half) {
            int cbl = cb & 2047;
            *(uint4*)((char*)yS + r * 2048 + (cbl ^ ((r & 7) << 4))) = u;
        }
    }
    ssq += __shfl_xor(ssq, 1); ssq += __shfl_xor(ssq, 2);
    ssq += __shfl_xor(ssq, 4); ssq += __shfl_xor(ssq, 8);
    if (cl == 0) scaleS[r] = rsqrtf(ssq / 2048.f + 1e-5f);
    __syncthreads();

    // phase 2: wave w handles 4 heads of its half
    #pragma unroll
    for (int hh = 0; hh < 4; ++hh) {
        int h = half * 16 + w * 4 + hh;
        int hl = h & 15;
        const short* wb = nwWT + (size_t)h * 4096;
        bf16x8 bfr[4][2];
        #pragma unroll
        for (int nt = 0; nt < 4; ++nt)
            #pragma unroll
            for (int ks = 0; ks < 2; ++ks)
                bfr[nt][ks] = *(const bf16x8*)(wb + (nt * 16 + l16) * 64 + ks * 32 + quad * 8);
        bf16x8 af[2];
        #pragma unroll
        for (int ks = 0; ks < 2; ++ks) {
            int cbl = hl * 128 + ks * 64 + quad * 16;
            af[ks] = *(const bf16x8*)((const char*)yS + l16 * 2048 + (cbl ^ ((l16 & 7) << 4)));
        }
        f32x4 acc[4];
        #pragma unroll
        for (int nt = 0; nt < 4; ++nt) acc[nt] = (f32x4){0.f, 0.f, 0.f, 0.f};
        #pragma unroll
        for (int ks = 0; ks < 2; ++ks)
            #pragma unroll
            for (int nt = 0; nt < 4; ++nt)
                acc[nt] = MFMA(af[ks], bfr[nt][ks], acc[nt]);
        #pragma unroll
        for (int nt = 0; nt < 4; ++nt) {
            float bv = o_b[h * 64 + nt * 16 + l16];
            #pragma unroll
            for (int rr = 0; rr < 4; ++rr) {
                int row = quad * 4 + rr;
                float o = acc[nt][rr] * silS[row * 32 + h] * scaleS[row] + bv;
                out[(size_t)(r0 + row) * 2048 + h * 64 + nt * 16 + l16] = o;
            }
        }
    }
}

extern "C" void kernel_launch(void* const* d_in, const int* in_sizes, int n_in,
                              void* d_out, int out_size, void* d_ws, size_t ws_size,
                              hipStream_t stream) {
    const float* hs_ab   = (const float*)d_in[0];
    const float* hs_g    = (const float*)d_in[1];
    const float* qst     = (const float*)d_in[2];
    const float* kst     = (const float*)d_in[3];
    const float* vst     = (const float*)d_in[4];
    const float* dt_w    = (const float*)d_in[5];
    const float* dt_b    = (const float*)d_in[6];
    const float* g_w     = (const float*)d_in[7];
    const float* g_b     = (const float*)d_in[8];
    const float* A_log   = (const float*)d_in[9];
    const float* dt_bias = (const float*)d_in[10];
    const float* norm_w  = (const float*)d_in[11];
    const float* o_w     = (const float*)d_in[12];
    const float* o_b     = (const float*)d_in[13];
    float* out = (float*)d_out;

    float* ws = (float*)d_ws;
    size_t off = 0;
    float* part   = ws + off; off += (size_t)2 * KSPLIT * 4096 * 32;  // 1M floats
    float* cumc   = ws + off; off += (size_t)NBCH * CHUNK;
    float* wvc    = ws + off; off += (size_t)NBCH * CHUNK;
    float* dtc    = ws + off; off += (size_t)NBCH * CHUNK;
    float* cd_ws  = ws + off; off += (size_t)NBCH;
    float* sp     = ws + off; off += (size_t)NBCH * 2 * 4096;
    float* Hp     = ws + off; off += (size_t)NBCH * 4096;
    short* nwWT   = (short*)(ws + off); off += (size_t)NH * 64 * 64 / 2;  // 131072 shorts

    short* ygb = (short*)sp;   // aliases sp (sp fully consumed by k_scan)

    k_proj<<<2 * KSPLIT * (BATCH * SEQ / 32) + NH, 256, 0, stream>>>(
        hs_ab, hs_g, dt_w, g_w, o_w, norm_w, part, nwWT);
    k_cumsum<<<NBCH, 256, 0, stream>>>(part, dt_b, dt_bias, A_log,
                                       cumc, wvc, dtc, cd_ws);
    k_states<<<NBCH * 2, 256, 0, stream>>>(kst, vst, wvc, sp);
    k_scan<<<BATCH * NH * 4096 / 256, 256, 0, stream>>>(sp, cd_ws, Hp);
    k_intra<<<NBCH, 512, 0, stream>>>(qst, kst, vst, cumc, dtc, Hp, ygb);
    k_out<<<2 * (BATCH * SEQ / 16), 256, 0, stream>>>(ygb, part, g_b, nwWT, o_b, out);
}

// Round 9
// 265.214 us; speedup vs baseline: 1.0546x; 1.0546x over previous
//
#include <hip/hip_runtime.h>
#include <math.h>

#define BATCH 2
#define SEQ   2048
#define NH    32
#define HID   2048
#define CHUNK 256
#define NCH   8
#define NBCH  (BATCH*NCH*NH)   // 512
#define PST   72               // padded bf16 LDS leading dim (b128-alignable)
#define BK    256
#define APST  264              // BK+8 shorts; row stride 528 B = 33*16 (b128-aligned)
#define KSPLIT 4
#define KSEG  (HID / KSPLIT)   // 512

typedef __attribute__((ext_vector_type(4))) float f32x4;
typedef __attribute__((ext_vector_type(8))) short bf16x8;
typedef unsigned int uint;
typedef unsigned short ushort;

__device__ __forceinline__ float softplusf(float x) {
    return x > 20.f ? x : log1pf(expf(x));
}

__device__ __forceinline__ short f2bf(float f) {
    union { float f; uint u; } v; v.f = f;
    uint r = v.u + 0x7FFF + ((v.u >> 16) & 1);
    return (short)(r >> 16);
}
__device__ __forceinline__ float bf2f(ushort s) {
    union { uint u; float f; } v; v.u = ((uint)s) << 16; return v.f;
}
// HW packed f32->bf16 RNE: 1 VALU op replacing ~8 (same rounding as manual
// add-0x7FFF-and-odd-bit, so bit-identical results).
__device__ __forceinline__ uint packbf2(float lo, float hi) {
    uint r;
    asm("v_cvt_pk_bf16_f32 %0, %1, %2" : "=v"(r) : "v"(lo), "v"(hi));
    return r;
}

__device__ __forceinline__ bf16x8 load_cvt8(const float* p, float scale) {
    float4 a = *(const float4*)p;
    float4 b = *(const float4*)(p + 4);
    union { bf16x8 v; uint u[4]; } r;
    r.u[0] = packbf2(a.x * scale, a.y * scale);
    r.u[1] = packbf2(a.z * scale, a.w * scale);
    r.u[2] = packbf2(b.x * scale, b.y * scale);
    r.u[3] = packbf2(b.z * scale, b.w * scale);
    return r.v;
}

__device__ __forceinline__ bf16x8 cvt8(float4 a, float4 b, float s) {
    union { bf16x8 v; uint u[4]; } r;
    r.u[0] = packbf2(a.x * s, a.y * s);
    r.u[1] = packbf2(a.z * s, a.w * s);
    r.u[2] = packbf2(b.x * s, b.y * s);
    r.u[3] = packbf2(b.z * s, b.w * s);
    return r.v;
}

#define MFMA(a,b,c) __builtin_amdgcn_mfma_f32_16x16x32_bf16((a),(b),(c),0,0,0)

// ---------------------------------------------------------------------------
// K1: dt/g projections as bf16 MFMA GEMM (split-K by 4), plus 32 trailing
// blocks that build nwWT[h][q][p] = bf16(o_w[h][p][q] * norm_w[h*64+p]).
// ---------------------------------------------------------------------------
__global__ __launch_bounds__(256) void k_proj(
    const float* __restrict__ hs_ab, const float* __restrict__ hs_g,
    const float* __restrict__ dt_w, const float* __restrict__ g_w,
    const float* __restrict__ o_w,  const float* __restrict__ norm_w,
    float* __restrict__ part, short* __restrict__ nwWT)
{
    __shared__ __align__(16) short As[32 * APST];
    __shared__ __align__(16) short Bs[32 * APST];
    int blk = blockIdx.x;
    int t = threadIdx.x;

    if (blk >= 2 * KSPLIT * 128) {
        // --- weight prep: transpose o_w per head, fold norm_w, cast bf16 ---
        int h = blk - 2 * KSPLIT * 128;
        float* tile = (float*)As;   // 64x64 f32 = 16 KB
        {
            int p = t >> 2, q0 = (t & 3) * 16;
            const float* wp = o_w + (size_t)h * 4096 + p * 64 + q0;
            #pragma unroll
            for (int i = 0; i < 4; ++i)
                *(float4*)(tile + p * 64 + q0 + i * 4) = *(const float4*)(wp + i * 4);
        }
        __syncthreads();
        int q = t >> 2, p0 = (t & 3) * 16;
        uint us[8];
        #pragma unroll
        for (int j = 0; j < 8; ++j) {
            float lo = tile[(p0 + 2*j    ) * 64 + q] * norm_w[h * 64 + p0 + 2*j];
            float hi = tile[(p0 + 2*j + 1) * 64 + q] * norm_w[h * 64 + p0 + 2*j + 1];
            us[j] = packbf2(lo, hi);
        }
        uint* dst = (uint*)(nwWT + (size_t)h * 4096 + q * 64 + p0);
        *(uint4*)dst       = make_uint4(us[0], us[1], us[2], us[3]);
        *(uint4*)(dst + 4) = make_uint4(us[4], us[5], us[6], us[7]);
        return;
    }

    int ksp = blk >> 8;          // 0..3 : K segment
    int rem = blk & 255;
    int which = rem >> 7;        // 0..1 : ab vs g
    int rt = rem & 127;          // 0..127 : 32-row tile
    int r0 = rt * 32;
    const float* Am = which ? hs_g : hs_ab;
    const float* W  = which ? g_w  : dt_w;
    int w = t >> 6, lane = t & 63, quad = lane >> 4, l16 = lane & 15;
    int mh = w & 1, nh = w >> 1;

    f32x4 acc = (f32x4){0.f, 0.f, 0.f, 0.f};

    for (int kc = ksp * KSEG; kc < ksp * KSEG + KSEG; kc += BK) {
        __syncthreads();
        {   // stage A: 32 rows x BK cols, bf16-packed
            int row = t >> 3, k0 = (t & 7) * 32;
            const float* src = Am + (size_t)(r0 + row) * HID + kc + k0;
            uint* dst = (uint*)(As + row * APST + k0);
            #pragma unroll
            for (int i = 0; i < 4; ++i) {
                float4 a = *(const float4*)(src + i * 8);
                float4 b = *(const float4*)(src + i * 8 + 4);
                dst[i*4+0] = packbf2(a.x, a.y); dst[i*4+1] = packbf2(a.z, a.w);
                dst[i*4+2] = packbf2(b.x, b.y); dst[i*4+3] = packbf2(b.z, b.w);
            }
        }
        if (t < 128) {   // stage W transposed: Bs[n][k] = W[kc+k][n], pair-packed
            int k2 = t * 2;
            const float* w0 = W + (size_t)(kc + k2) * NH;
            const float* w1 = w0 + NH;
            #pragma unroll
            for (int n = 0; n < 32; n += 4) {
                float4 a = *(const float4*)(w0 + n);
                float4 b = *(const float4*)(w1 + n);
                *((uint*)(Bs + (n+0) * APST + k2)) = packbf2(a.x, b.x);
                *((uint*)(Bs + (n+1) * APST + k2)) = packbf2(a.y, b.y);
                *((uint*)(Bs + (n+2) * APST + k2)) = packbf2(a.z, b.z);
                *((uint*)(Bs + (n+3) * APST + k2)) = packbf2(a.w, b.w);
            }
        }
        __syncthreads();
        #pragma unroll
        for (int ks = 0; ks < BK / 32; ++ks) {
            bf16x8 af = *(const bf16x8*)(As + (mh*16 + l16) * APST + ks*32 + quad*8);
            bf16x8 bf = *(const bf16x8*)(Bs + (nh*16 + l16) * APST + ks*32 + quad*8);
            acc = MFMA(af, bf, acc);
        }
    }

    int n = nh * 16 + l16;
    int Rb = r0 + mh * 16 + quad * 4;
    float* pd = part + ((size_t)(which * KSPLIT + ksp) * 4096 + Rb) * 32 + n;
    #pragma unroll
    for (int r = 0; r < 4; ++r)
        pd[r * 32] = acc[r];
}

// ---------------------------------------------------------------------------
// K2: per (b,c,h): sum dt split-K partials + bias + softplus, wave-shfl scan
// of dt*A; emits chunk-ordered cum/dt/w and chunk decay.
// ---------------------------------------------------------------------------
__global__ __launch_bounds__(256) void k_cumsum(
    const float* __restrict__ part, const float* __restrict__ dt_b,
    const float* __restrict__ dt_bias, const float* __restrict__ A_log,
    float* __restrict__ cumc, float* __restrict__ wvc,
    float* __restrict__ dtc, float* __restrict__ cd)
{
    __shared__ float wsum[4];
    int bch = blockIdx.x;
    int h = bch & 31, c = (bch >> 5) & 7, b = bch >> 8;
    int t = threadIdx.x;
    int w = t >> 6, lane = t & 63;
    int rid = (b * SEQ + c * CHUNK + t) * 32 + h;
    float s = part[rid] + part[131072 + rid] + part[262144 + rid] + part[393216 + rid];
    float dt_l = softplusf(s + dt_b[h] + dt_bias[h]);
    float A = -expf(A_log[h]);
    float v = dt_l * A;
    #pragma unroll
    for (int off = 1; off < 64; off <<= 1) {
        float u = __shfl_up(v, off);
        if (lane >= off) v += u;
    }
    if (lane == 63) wsum[w] = v;
    __syncthreads();
    float pre = 0.f;
    #pragma unroll
    for (int i = 0; i < 3; ++i)
        if (i < w) pre += wsum[i];
    float cum = v + pre;
    float tot = wsum[0] + wsum[1] + wsum[2] + wsum[3];
    size_t o = (size_t)bch * CHUNK + t;
    cumc[o] = cum;
    wvc[o] = expf(tot - cum) * dt_l;
    dtc[o] = dt_l;
    if (t == 255) cd[bch] = expf(tot);
}

// ---------------------------------------------------------------------------
// K4: partial chunk states (invB computed inline)
// ---------------------------------------------------------------------------
__global__ __launch_bounds__(256) void k_states(
    const float* __restrict__ kst, const float* __restrict__ vst,
    const float* __restrict__ wvc, float* __restrict__ sp)
{
    __shared__ __align__(16) float kS[64 * 64];
    __shared__ __align__(16) float xS[64 * 64];
    int blk = blockIdx.x;
    int half = blk & 1, bch = blk >> 1;
    int h = bch & 31, c = (bch >> 5) & 7, b = bch >> 8;
    int t = threadIdx.x;
    size_t rowbase = (size_t)b * SEQ + c * CHUNK + half * 128;
    int pg = (t & 15) * 4, ng = (t >> 4) * 4;
    float acc[4][4];
    #pragma unroll
    for (int i = 0; i < 4; ++i)
        #pragma unroll
        for (int j = 0; j < 4; ++j) acc[i][j] = 0.f;

    for (int tt = 0; tt < 2; ++tt) {
        int r0 = t >> 4;
        int c4 = (t & 15) * 4;
        #pragma unroll
        for (int i = 0; i < 4; ++i) {
            int row = r0 + i * 16;
            size_t grow = (rowbase + tt * 64 + row) * NH + h;
            float wv = wvc[(size_t)bch * CHUNK + half * 128 + tt * 64 + row];
            float4 kv = *(const float4*)(kst + grow * 64 + c4);
            float4 xv = *(const float4*)(vst + grow * 64 + c4);
            float ssq = kv.x*kv.x + kv.y*kv.y + kv.z*kv.z + kv.w*kv.w;
            ssq += __shfl_xor(ssq, 1); ssq += __shfl_xor(ssq, 2);
            ssq += __shfl_xor(ssq, 4); ssq += __shfl_xor(ssq, 8);
            float ib = 1.f / fmaxf(sqrtf(ssq), 1e-12f);
            *(float4*)(kS + row * 64 + c4) =
                make_float4(kv.x * ib, kv.y * ib, kv.z * ib, kv.w * ib);
            *(float4*)(xS + row * 64 + c4) =
                make_float4(xv.x * wv, xv.y * wv, xv.z * wv, xv.w * wv);
        }
        __syncthreads();
        for (int ll = 0; ll < 64; ++ll) {
            float4 x4 = *(const float4*)(xS + ll * 64 + pg);
            float4 k4 = *(const float4*)(kS + ll * 64 + ng);
            acc[0][0] += x4.x * k4.x; acc[0][1] += x4.x * k4.y;
            acc[0][2] += x4.x * k4.z; acc[0][3] += x4.x * k4.w;
            acc[1][0] += x4.y * k4.x; acc[1][1] += x4.y * k4.y;
            acc[1][2] += x4.y * k4.z; acc[1][3] += x4.y * k4.w;
            acc[2][0] += x4.z * k4.x; acc[2][1] += x4.z * k4.y;
            acc[2][2] += x4.z * k4.z; acc[2][3] += x4.z * k4.w;
            acc[3][0] += x4.w * k4.x; acc[3][1] += x4.w * k4.y;
            acc[3][2] += x4.w * k4.z; acc[3][3] += x4.w * k4.w;
        }
        __syncthreads();
    }
    size_t obase = (size_t)blk * 4096;
    #pragma unroll
    for (int i = 0; i < 4; ++i)
        *(float4*)(sp + obase + (pg + i) * 64 + ng) =
            make_float4(acc[i][0], acc[i][1], acc[i][2], acc[i][3]);
}

// ---------------------------------------------------------------------------
// K5: inter-chunk scan
// ---------------------------------------------------------------------------
__global__ __launch_bounds__(256) void k_scan(
    const float* __restrict__ sp, const float* __restrict__ cd,
    float* __restrict__ Hp)
{
    size_t id = (size_t)blockIdx.x * 256 + threadIdx.x;
    size_t bh = id >> 12, pn = id & 4095;
    size_t b = bh >> 5, h = bh & 31;
    float carry = 0.f;
    for (int c = 0; c < NCH; ++c) {
        size_t bch = (b * NCH + c) * NH + h;
        float st = sp[(bch * 2) * 4096 + pn] + sp[(bch * 2 + 1) * 4096 + pn];
        Hp[bch * 4096 + pn] = carry;
        carry = cd[bch] * carry + st;
    }
}

// ---------------------------------------------------------------------------
// K6: MFMA intra-chunk + H_prev. R9: revert to R4 structure (best of 5
// variants: R3 41.1 / R4 40.4 / R6 46.6 / R7 61.3 / R8 48.6 us) —
// 256 thr, dbuf B/XT (1 barrier per st), register prefetch. All bf16
// packing now via v_cvt_pk_bf16_f32 (1 op per pair vs ~8 manual).
// ---------------------------------------------------------------------------
__global__ __launch_bounds__(256, 2) void k_intra(
    const float* __restrict__ qst, const float* __restrict__ kst,
    const float* __restrict__ vst,
    const float* __restrict__ cumc, const float* __restrict__ dtc,
    const float* __restrict__ Hp,
    short* __restrict__ ygb)
{
    __shared__ __align__(16) short B_s[2][64 * PST];
    __shared__ __align__(16) short XT_s[2][64 * PST];
    __shared__ __align__(16) short P_s[4 * 32 * PST];
    __shared__ float sCum[256];
    __shared__ float sDt[256];

    int bch = blockIdx.x;
    int h = bch & 31, c = (bch >> 5) & 7, b = bch >> 8;
    int t = threadIdx.x;
    int w = t >> 6, lane = t & 63;
    int quad = lane >> 4, l16 = lane & 15;
    size_t rowbase = (size_t)b * SEQ + c * CHUNK;

    sCum[t] = cumc[(size_t)bch * CHUNK + t];
    sDt[t]  = dtc[(size_t)bch * CHUNK + t];

    // staging thread mapping (constant across st)
    int ssA = t >> 2, q4A = (t & 3) * 16;      // B_s: row ssA, 16-col group
    int ss2 = t & 31, p0 = (t >> 5) * 8;       // XT: rows 2*ss2(+1), 8 p's

    // prefetch k/v for st=0 (flies under the Q/Hp prologue)
    float4 kv[4], xa[2], xb[2];
    {
        size_t gK = (rowbase + ssA) * NH + h;
        const float4* kp = (const float4*)(kst + gK * 64 + q4A);
        kv[0] = kp[0]; kv[1] = kp[1]; kv[2] = kp[2]; kv[3] = kp[3];
        size_t g0 = (rowbase + 2 * ss2) * NH + h;
        const float* vp0 = vst + g0 * 64 + p0;
        const float* vp1 = vst + (g0 + NH) * 64 + p0;
        xa[0] = *(const float4*)vp0; xa[1] = *(const float4*)(vp0 + 4);
        xb[0] = *(const float4*)vp1; xb[1] = *(const float4*)(vp1 + 4);
    }

    bf16x8 cf[2][2][2];
    #pragma unroll
    for (int is = 0; is < 2; ++is) {
        int strip = is ? (7 - w) : w;
        #pragma unroll
        for (int lt = 0; lt < 2; ++lt) {
            int l = strip * 32 + lt * 16 + l16;
            size_t grow = (rowbase + l) * NH + h;
            const float* qp = qst + grow * 64 + quad * 8;
            float4 a  = *(const float4*)qp;
            float4 bq = *(const float4*)(qp + 4);
            float4 c2 = *(const float4*)(qp + 32);
            float4 d  = *(const float4*)(qp + 36);
            float ssq = a.x*a.x + a.y*a.y + a.z*a.z + a.w*a.w
                      + bq.x*bq.x + bq.y*bq.y + bq.z*bq.z + bq.w*bq.w
                      + c2.x*c2.x + c2.y*c2.y + c2.z*c2.z + c2.w*c2.w
                      + d.x*d.x + d.y*d.y + d.z*d.z + d.w*d.w;
            ssq += __shfl_xor(ssq, 16);
            ssq += __shfl_xor(ssq, 32);
            float ic = 1.f / fmaxf(sqrtf(ssq), 1e-12f);
            cf[is][lt][0] = cvt8(a, bq, ic);
            cf[is][lt][1] = cvt8(c2, d, ic);
        }
    }

    f32x4 acc[2][2][4];
    #pragma unroll
    for (int is = 0; is < 2; ++is)
        #pragma unroll
        for (int lt = 0; lt < 2; ++lt)
            #pragma unroll
            for (int pt = 0; pt < 4; ++pt)
                acc[is][lt][pt] = (f32x4){0.f, 0.f, 0.f, 0.f};

    {
        bf16x8 hf[4][2];
        #pragma unroll
        for (int pt = 0; pt < 4; ++pt) {
            const float* hp = Hp + (size_t)bch * 4096 + (pt * 16 + l16) * 64 + quad * 8;
            hf[pt][0] = load_cvt8(hp, 1.f);
            hf[pt][1] = load_cvt8(hp + 32, 1.f);
        }
        #pragma unroll
        for (int is = 0; is < 2; ++is)
            #pragma unroll
            for (int lt = 0; lt < 2; ++lt)
                #pragma unroll
                for (int pt = 0; pt < 4; ++pt) {
                    acc[is][lt][pt] = MFMA(cf[is][lt][0], hf[pt][0], acc[is][lt][pt]);
                    acc[is][lt][pt] = MFMA(cf[is][lt][1], hf[pt][1], acc[is][lt][pt]);
                }
    }
    __syncthreads();   // sCum/sDt now visible to all waves
    #pragma unroll
    for (int is = 0; is < 2; ++is) {
        int strip = is ? (7 - w) : w;
        #pragma unroll
        for (int lt = 0; lt < 2; ++lt) {
            float e[4];
            #pragma unroll
            for (int r = 0; r < 4; ++r)
                e[r] = __expf(sCum[strip * 32 + lt * 16 + quad * 4 + r]);
            #pragma unroll
            for (int pt = 0; pt < 4; ++pt)
                #pragma unroll
                for (int r = 0; r < 4; ++r)
                    acc[is][lt][pt][r] *= e[r];
        }
    }

    short* Pw = P_s + w * 32 * PST;

    #pragma unroll
    for (int st = 0; st < 4; ++st) {
        // issue next-tile global loads first (hide under pack+barrier+compute)
        float4 kvN[4], xaN[2], xbN[2];
        if (st < 3) {
            size_t gK = (rowbase + (st + 1) * 64 + ssA) * NH + h;
            const float4* kp = (const float4*)(kst + gK * 64 + q4A);
            kvN[0] = kp[0]; kvN[1] = kp[1]; kvN[2] = kp[2]; kvN[3] = kp[3];
            size_t g0 = (rowbase + (st + 1) * 64 + 2 * ss2) * NH + h;
            const float* vp0 = vst + g0 * 64 + p0;
            const float* vp1 = vst + (g0 + NH) * 64 + p0;
            xaN[0] = *(const float4*)vp0; xaN[1] = *(const float4*)(vp0 + 4);
            xbN[0] = *(const float4*)vp1; xbN[1] = *(const float4*)(vp1 + 4);
        }

        short* Bb = B_s[st & 1];
        short* Xb = XT_s[st & 1];
        {   // pack K-hat (bf16) into Bb from regs
            float ssq = kv[0].x*kv[0].x + kv[0].y*kv[0].y + kv[0].z*kv[0].z + kv[0].w*kv[0].w
                      + kv[1].x*kv[1].x + kv[1].y*kv[1].y + kv[1].z*kv[1].z + kv[1].w*kv[1].w
                      + kv[2].x*kv[2].x + kv[2].y*kv[2].y + kv[2].z*kv[2].z + kv[2].w*kv[2].w
                      + kv[3].x*kv[3].x + kv[3].y*kv[3].y + kv[3].z*kv[3].z + kv[3].w*kv[3].w;
            ssq += __shfl_xor(ssq, 1);
            ssq += __shfl_xor(ssq, 2);
            float ib = 1.f / fmaxf(sqrtf(ssq), 1e-12f);
            uint u[8];
            u[0] = packbf2(kv[0].x * ib, kv[0].y * ib); u[1] = packbf2(kv[0].z * ib, kv[0].w * ib);
            u[2] = packbf2(kv[1].x * ib, kv[1].y * ib); u[3] = packbf2(kv[1].z * ib, kv[1].w * ib);
            u[4] = packbf2(kv[2].x * ib, kv[2].y * ib); u[5] = packbf2(kv[2].z * ib, kv[2].w * ib);
            u[6] = packbf2(kv[3].x * ib, kv[3].y * ib); u[7] = packbf2(kv[3].z * ib, kv[3].w * ib);
            uint* dst = (uint*)(Bb + ssA * PST + q4A);
            *(uint4*)dst = make_uint4(u[0], u[1], u[2], u[3]);
            *(uint4*)(dst + 4) = make_uint4(u[4], u[5], u[6], u[7]);
        }
        {   // pack dt-scaled X^T (bf16 pair-packed) into Xb from regs
            float dt0 = sDt[st * 64 + 2 * ss2];
            float dt1 = sDt[st * 64 + 2 * ss2 + 1];
            float x0[8] = {xa[0].x, xa[0].y, xa[0].z, xa[0].w,
                           xa[1].x, xa[1].y, xa[1].z, xa[1].w};
            float x1[8] = {xb[0].x, xb[0].y, xb[0].z, xb[0].w,
                           xb[1].x, xb[1].y, xb[1].z, xb[1].w};
            uint* xt = (uint*)Xb;
            #pragma unroll
            for (int i = 0; i < 8; ++i)
                xt[(p0 + i) * (PST / 2) + ss2] = packbf2(x0[i] * dt0, x1[i] * dt1);
        }
        __syncthreads();

        bf16x8 xf[4][2];
        #pragma unroll
        for (int pt = 0; pt < 4; ++pt) {
            #pragma unroll
            for (int ks = 0; ks < 2; ++ks)
                xf[pt][ks] = *(const bf16x8*)(Xb + (pt * 16 + l16) * PST + ks * 32 + quad * 8);
        }

        #pragma unroll
        for (int is = 0; is < 2; ++is) {
            int strip = is ? (7 - w) : w;
            int L0 = strip * 32;
            if (L0 + 31 < st * 64) continue;

            #pragma unroll
            for (int lt = 0; lt < 2; ++lt) {
                int Lt = L0 + lt * 16;
                float cl = sCum[Lt + l16];
                int lrow = lt * 16 + l16;
                #pragma unroll
                for (int mt = 0; mt < 4; ++mt) {
                    int S0 = st * 64 + mt * 16;
                    uint* pdst = (uint*)(Pw + lrow * PST + mt * 16 + quad * 4);
                    if (S0 > Lt + 15) {
                        *(uint2*)pdst = make_uint2(0u, 0u);
                        continue;
                    }
                    f32x4 sa = (f32x4){0.f, 0.f, 0.f, 0.f};
                    bf16x8 af0 = *(const bf16x8*)(Bb + (mt * 16 + l16) * PST + quad * 8);
                    bf16x8 af1 = *(const bf16x8*)(Bb + (mt * 16 + l16) * PST + 32 + quad * 8);
                    sa = MFMA(af0, cf[is][lt][0], sa);
                    sa = MFMA(af1, cf[is][lt][1], sa);
                    float vals[4];
                    #pragma unroll
                    for (int r = 0; r < 4; ++r) {
                        int s = S0 + quad * 4 + r;
                        float v = sa[r] * __expf(cl - sCum[s]);
                        vals[r] = (Lt + l16 >= s) ? v : 0.f;
                    }
                    *(uint2*)pdst = make_uint2(packbf2(vals[0], vals[1]),
                                               packbf2(vals[2], vals[3]));
                }
            }
            #pragma unroll
            for (int lt = 0; lt < 2; ++lt) {
                int Lmax = L0 + lt * 16 + 15;
                #pragma unroll
                for (int ks = 0; ks < 2; ++ks) {
                    if (st * 64 + ks * 32 > Lmax) continue;
                    bf16x8 af = *(const bf16x8*)(Pw + (lt * 16 + l16) * PST + ks * 32 + quad * 8);
                    #pragma unroll
                    for (int pt = 0; pt < 4; ++pt)
                        acc[is][lt][pt] = MFMA(af, xf[pt][ks], acc[is][lt][pt]);
                }
            }
        }

        if (st < 3) {
            kv[0] = kvN[0]; kv[1] = kvN[1]; kv[2] = kvN[2]; kv[3] = kvN[3];
            xa[0] = xaN[0]; xa[1] = xaN[1];
            xb[0] = xbN[0]; xb[1] = xbN[1];
        }
    }

    #pragma unroll
    for (int is = 0; is < 2; ++is) {
        int strip = is ? (7 - w) : w;
        #pragma unroll
        for (int lt = 0; lt < 2; ++lt)
            #pragma unroll
            for (int pt = 0; pt < 4; ++pt)
                #pragma unroll
                for (int r = 0; r < 4; ++r) {
                    int l = strip * 32 + lt * 16 + quad * 4 + r;
                    int p = pt * 16 + l16;
                    ygb[((rowbase + l) * NH + h) * 64 + p] = f2bf(acc[is][lt][pt][r]);
                }
    }
}

// ---------------------------------------------------------------------------
// K7: fused gate + RMSNorm + per-head o_proj.
// ---------------------------------------------------------------------------
__global__ __launch_bounds__(256) void k_out(
    const short* __restrict__ ygb, const float* __restrict__ part,
    const float* __restrict__ g_b, const short* __restrict__ nwWT,
    const float* __restrict__ o_b, float* __restrict__ out)
{
    __shared__ __align__(16) short yS[16 * 1024];   // 16 rows x own head-half
    __shared__ float silS[16 * 32];
    __shared__ float scaleS[16];
    int blk = blockIdx.x;
    int half = blk & 1, rt = blk >> 1;
    int r0 = rt * 16;
    int t = threadIdx.x;
    int w = t >> 6, lane = t & 63, quad = lane >> 4, l16 = lane & 15;

    // phase 0: gates (sum g split-K partials + bias, silu) for all 32 heads
    const float* gpart = part + 4 * 131072;
    #pragma unroll
    for (int ii = 0; ii < 2; ++ii) {
        int idx = t + ii * 256;                 // (row 0..15, h 0..31)
        int rr = idx >> 5, hh = idx & 31;
        int rid = (r0 + rr) * 32 + hh;
        float g = gpart[rid] + gpart[131072 + rid] + gpart[262144 + rid]
                + gpart[393216 + rid] + g_b[hh];
        silS[idx] = g / (1.f + expf(-g));
    }
    __syncthreads();

    // phase 1: stream full rows, gated sumsq; stash own half to LDS (swizzled)
    int r = t >> 4, cl = t & 15;
    const char* yrow = (const char*)(ygb + (size_t)(r0 + r) * 2048);
    float ssq = 0.f;
    #pragma unroll
    for (int i = 0; i < 16; ++i) {
        int cb = i * 256 + cl * 16;             // byte offset 0..4095
        uint4 u = *(const uint4*)(yrow + cb);
        float s = silS[r * 32 + (cb >> 7)];
        float v0 = bf2f((ushort)(u.x & 0xFFFF)) * s, v1 = bf2f((ushort)(u.x >> 16)) * s;
        float v2 = bf2f((ushort)(u.y & 0xFFFF)) * s, v3 = bf2f((ushort)(u.y >> 16)) * s;
        float v4 = bf2f((ushort)(u.z & 0xFFFF)) * s, v5 = bf2f((ushort)(u.z >> 16)) * s;
        float v6 = bf2f((ushort)(u.w & 0xFFFF)) * s, v7 = bf2f((ushort)(u.w >> 16)) * s;
        ssq += v0*v0 + v1*v1 + v2*v2 + v3*v3 + v4*v4 + v5*v5 + v6*v6 + v7*v7;
        if ((cb >> 11) == half) {
            int cbl = cb & 2047;
            *(uint4*)((char*)yS + r * 2048 + (cbl ^ ((r & 7) << 4))) = u;
        }
    }
    ssq += __shfl_xor(ssq, 1); ssq += __shfl_xor(ssq, 2);
    ssq += __shfl_xor(ssq, 4); ssq += __shfl_xor(ssq, 8);
    if (cl == 0) scaleS[r] = rsqrtf(ssq / 2048.f + 1e-5f);
    __syncthreads();

    // phase 2: wave w handles 4 heads of its half
    #pragma unroll
    for (int hh = 0; hh < 4; ++hh) {
        int h = half * 16 + w * 4 + hh;
        int hl = h & 15;
        const short* wb = nwWT + (size_t)h * 4096;
        bf16x8 bfr[4][2];
        #pragma unroll
        for (int nt = 0; nt < 4; ++nt)
            #pragma unroll
            for (int ks = 0; ks < 2; ++ks)
                bfr[nt][ks] = *(const bf16x8*)(wb + (nt * 16 + l16) * 64 + ks * 32 + quad * 8);
        bf16x8 af[2];
        #pragma unroll
        for (int ks = 0; ks < 2; ++ks) {
            int cbl = hl * 128 + ks * 64 + quad * 16;
            af[ks] = *(const bf16x8*)((const char*)yS + l16 * 2048 + (cbl ^ ((l16 & 7) << 4)));
        }
        f32x4 acc[4];
        #pragma unroll
        for (int nt = 0; nt < 4; ++nt) acc[nt] = (f32x4){0.f, 0.f, 0.f, 0.f};
        #pragma unroll
        for (int ks = 0; ks < 2; ++ks)
            #pragma unroll
            for (int nt = 0; nt < 4; ++nt)
                acc[nt] = MFMA(af[ks], bfr[nt][ks], acc[nt]);
        #pragma unroll
        for (int nt = 0; nt < 4; ++nt) {
            float bv = o_b[h * 64 + nt * 16 + l16];
            #pragma unroll
            for (int rr = 0; rr < 4; ++rr) {
                int row = quad * 4 + rr;
                float o = acc[nt][rr] * silS[row * 32 + h] * scaleS[row] + bv;
                out[(size_t)(r0 + row) * 2048 + h * 64 + nt * 16 + l16] = o;
            }
        }
    }
}

extern "C" void kernel_launch(void* const* d_in, const int* in_sizes, int n_in,
                              void* d_out, int out_size, void* d_ws, size_t ws_size,
                              hipStream_t stream) {
    const float* hs_ab   = (const float*)d_in[0];
    const float* hs_g    = (const float*)d_in[1];
    const float* qst     = (const float*)d_in[2];
    const float* kst     = (const float*)d_in[3];
    const float* vst     = (const float*)d_in[4];
    const float* dt_w    = (const float*)d_in[5];
    const float* dt_b    = (const float*)d_in[6];
    const float* g_w     = (const float*)d_in[7];
    const float* g_b     = (const float*)d_in[8];
    const float* A_log   = (const float*)d_in[9];
    const float* dt_bias = (const float*)d_in[10];
    const float* norm_w  = (const float*)d_in[11];
    const float* o_w     = (const float*)d_in[12];
    const float* o_b     = (const float*)d_in[13];
    float* out = (float*)d_out;

    float* ws = (float*)d_ws;
    size_t off = 0;
    float* part   = ws + off; off += (size_t)2 * KSPLIT * 4096 * 32;  // 1M floats
    float* cumc   = ws + off; off += (size_t)NBCH * CHUNK;
    float* wvc    = ws + off; off += (size_t)NBCH * CHUNK;
    float* dtc    = ws + off; off += (size_t)NBCH * CHUNK;
    float* cd_ws  = ws + off; off += (size_t)NBCH;
    float* sp     = ws + off; off += (size_t)NBCH * 2 * 4096;
    float* Hp     = ws + off; off += (size_t)NBCH * 4096;
    short* nwWT   = (short*)(ws + off); off += (size_t)NH * 64 * 64 / 2;  // 131072 shorts

    short* ygb = (short*)sp;   // aliases sp (sp fully consumed by k_scan)

    k_proj<<<2 * KSPLIT * (BATCH * SEQ / 32) + NH, 256, 0, stream>>>(
        hs_ab, hs_g, dt_w, g_w, o_w, norm_w, part, nwWT);
    k_cumsum<<<NBCH, 256, 0, stream>>>(part, dt_b, dt_bias, A_log,
                                       cumc, wvc, dtc, cd_ws);
    k_states<<<NBCH * 2, 256, 0, stream>>>(kst, vst, wvc, sp);
    k_scan<<<BATCH * NH * 4096 / 256, 256, 0, stream>>>(sp, cd_ws, Hp);
    k_intra<<<NBCH, 256, 0, stream>>>(qst, kst, vst, cumc, dtc, Hp, ygb);
    k_out<<<2 * (BATCH * SEQ / 16), 256, 0, stream>>>(ygb, part, g_b, nwWT, o_b, out);
}

// Round 10
// 260.491 us; speedup vs baseline: 1.0738x; 1.0181x over previous
//
#include <hip/hip_runtime.h>
#include <math.h>

#define BATCH 2
#define SEQ   2048
#define NH    32
#define HID   2048
#define CHUNK 256
#define NCH   8
#define NBCH  (BATCH*NCH*NH)   // 512
#define PST   72               // padded bf16 LDS leading dim (b128-alignable)
#define BK    256
#define APST  264              // BK+8 shorts; row stride 528 B = 33*16 (b128-aligned)
#define KSPLIT 4
#define KSEG  (HID / KSPLIT)   // 512

typedef __attribute__((ext_vector_type(4))) float f32x4;
typedef __attribute__((ext_vector_type(8))) short bf16x8;
typedef unsigned int uint;
typedef unsigned short ushort;

__device__ __forceinline__ float softplusf(float x) {
    return x > 20.f ? x : log1pf(expf(x));
}

__device__ __forceinline__ short f2bf(float f) {
    union { float f; uint u; } v; v.f = f;
    uint r = v.u + 0x7FFF + ((v.u >> 16) & 1);
    return (short)(r >> 16);
}
__device__ __forceinline__ float bf2f(ushort s) {
    union { uint u; float f; } v; v.u = ((uint)s) << 16; return v.f;
}
// HW packed f32->bf16 RNE: 1 VALU op replacing ~8 (bit-identical rounding,
// confirmed by unchanged absmax in R9).
__device__ __forceinline__ uint packbf2(float lo, float hi) {
    uint r;
    asm("v_cvt_pk_bf16_f32 %0, %1, %2" : "=v"(r) : "v"(lo), "v"(hi));
    return r;
}

__device__ __forceinline__ bf16x8 load_cvt8(const float* p, float scale) {
    float4 a = *(const float4*)p;
    float4 b = *(const float4*)(p + 4);
    union { bf16x8 v; uint u[4]; } r;
    r.u[0] = packbf2(a.x * scale, a.y * scale);
    r.u[1] = packbf2(a.z * scale, a.w * scale);
    r.u[2] = packbf2(b.x * scale, b.y * scale);
    r.u[3] = packbf2(b.z * scale, b.w * scale);
    return r.v;
}

__device__ __forceinline__ bf16x8 cvt8(float4 a, float4 b, float s) {
    union { bf16x8 v; uint u[4]; } r;
    r.u[0] = packbf2(a.x * s, a.y * s);
    r.u[1] = packbf2(a.z * s, a.w * s);
    r.u[2] = packbf2(b.x * s, b.y * s);
    r.u[3] = packbf2(b.z * s, b.w * s);
    return r.v;
}

#define MFMA(a,b,c) __builtin_amdgcn_mfma_f32_16x16x32_bf16((a),(b),(c),0,0,0)

// ---------------------------------------------------------------------------
// K1: dt/g projections as bf16 MFMA GEMM (split-K by 4), plus 32 trailing
// blocks that build nwWT[h][q][p] = bf16(o_w[h][p][q] * norm_w[h*64+p]).
// ---------------------------------------------------------------------------
__global__ __launch_bounds__(256) void k_proj(
    const float* __restrict__ hs_ab, const float* __restrict__ hs_g,
    const float* __restrict__ dt_w, const float* __restrict__ g_w,
    const float* __restrict__ o_w,  const float* __restrict__ norm_w,
    float* __restrict__ part, short* __restrict__ nwWT)
{
    __shared__ __align__(16) short As[32 * APST];
    __shared__ __align__(16) short Bs[32 * APST];
    int blk = blockIdx.x;
    int t = threadIdx.x;

    if (blk >= 2 * KSPLIT * 128) {
        // --- weight prep: transpose o_w per head, fold norm_w, cast bf16 ---
        int h = blk - 2 * KSPLIT * 128;
        float* tile = (float*)As;   // 64x64 f32 = 16 KB
        {
            int p = t >> 2, q0 = (t & 3) * 16;
            const float* wp = o_w + (size_t)h * 4096 + p * 64 + q0;
            #pragma unroll
            for (int i = 0; i < 4; ++i)
                *(float4*)(tile + p * 64 + q0 + i * 4) = *(const float4*)(wp + i * 4);
        }
        __syncthreads();
        int q = t >> 2, p0 = (t & 3) * 16;
        uint us[8];
        #pragma unroll
        for (int j = 0; j < 8; ++j) {
            float lo = tile[(p0 + 2*j    ) * 64 + q] * norm_w[h * 64 + p0 + 2*j];
            float hi = tile[(p0 + 2*j + 1) * 64 + q] * norm_w[h * 64 + p0 + 2*j + 1];
            us[j] = packbf2(lo, hi);
        }
        uint* dst = (uint*)(nwWT + (size_t)h * 4096 + q * 64 + p0);
        *(uint4*)dst       = make_uint4(us[0], us[1], us[2], us[3]);
        *(uint4*)(dst + 4) = make_uint4(us[4], us[5], us[6], us[7]);
        return;
    }

    int ksp = blk >> 8;          // 0..3 : K segment
    int rem = blk & 255;
    int which = rem >> 7;        // 0..1 : ab vs g
    int rt = rem & 127;          // 0..127 : 32-row tile
    int r0 = rt * 32;
    const float* Am = which ? hs_g : hs_ab;
    const float* W  = which ? g_w  : dt_w;
    int w = t >> 6, lane = t & 63, quad = lane >> 4, l16 = lane & 15;
    int mh = w & 1, nh = w >> 1;

    f32x4 acc = (f32x4){0.f, 0.f, 0.f, 0.f};

    for (int kc = ksp * KSEG; kc < ksp * KSEG + KSEG; kc += BK) {
        __syncthreads();
        {   // stage A: 32 rows x BK cols, bf16-packed
            int row = t >> 3, k0 = (t & 7) * 32;
            const float* src = Am + (size_t)(r0 + row) * HID + kc + k0;
            uint* dst = (uint*)(As + row * APST + k0);
            #pragma unroll
            for (int i = 0; i < 4; ++i) {
                float4 a = *(const float4*)(src + i * 8);
                float4 b = *(const float4*)(src + i * 8 + 4);
                dst[i*4+0] = packbf2(a.x, a.y); dst[i*4+1] = packbf2(a.z, a.w);
                dst[i*4+2] = packbf2(b.x, b.y); dst[i*4+3] = packbf2(b.z, b.w);
            }
        }
        if (t < 128) {   // stage W transposed: Bs[n][k] = W[kc+k][n], pair-packed
            int k2 = t * 2;
            const float* w0 = W + (size_t)(kc + k2) * NH;
            const float* w1 = w0 + NH;
            #pragma unroll
            for (int n = 0; n < 32; n += 4) {
                float4 a = *(const float4*)(w0 + n);
                float4 b = *(const float4*)(w1 + n);
                *((uint*)(Bs + (n+0) * APST + k2)) = packbf2(a.x, b.x);
                *((uint*)(Bs + (n+1) * APST + k2)) = packbf2(a.y, b.y);
                *((uint*)(Bs + (n+2) * APST + k2)) = packbf2(a.z, b.z);
                *((uint*)(Bs + (n+3) * APST + k2)) = packbf2(a.w, b.w);
            }
        }
        __syncthreads();
        #pragma unroll
        for (int ks = 0; ks < BK / 32; ++ks) {
            bf16x8 af = *(const bf16x8*)(As + (mh*16 + l16) * APST + ks*32 + quad*8);
            bf16x8 bf = *(const bf16x8*)(Bs + (nh*16 + l16) * APST + ks*32 + quad*8);
            acc = MFMA(af, bf, acc);
        }
    }

    int n = nh * 16 + l16;
    int Rb = r0 + mh * 16 + quad * 4;
    float* pd = part + ((size_t)(which * KSPLIT + ksp) * 4096 + Rb) * 32 + n;
    #pragma unroll
    for (int r = 0; r < 4; ++r)
        pd[r * 32] = acc[r];
}

// ---------------------------------------------------------------------------
// K4 (new): chunk-state GEMM via MFMA, with k_cumsum ABSORBED.
// Grid = NBCH*2 (one block per half-chunk). Prologue: full 256-row scan of
// dt*A (both halves compute it; each writes its own rows of cumc/dtc).
// Then states[p][n] = sum_s x[s][p]*wv[s] * khat[s][n] as M=N=64, K=128
// bf16 MFMA (was a 2048-FMA/thread VALU loop with 256 ds_read_b128/wave,
// ~20us LDS-bound; now ~16 MFMA/wave at the ~11us memory floor).
// ---------------------------------------------------------------------------
__global__ __launch_bounds__(256) void k_states(
    const float* __restrict__ part, const float* __restrict__ dt_b,
    const float* __restrict__ dt_bias, const float* __restrict__ A_log,
    const float* __restrict__ kst, const float* __restrict__ vst,
    float* __restrict__ cumc, float* __restrict__ dtc, float* __restrict__ cd,
    float* __restrict__ sp)
{
    __shared__ __align__(16) short kT[64 * PST];    // khat^T  [n][s]
    __shared__ __align__(16) short xwT[64 * PST];   // (x*wv)^T [p][s]
    __shared__ float wsum[4];
    __shared__ float sWv[256];

    int blk = blockIdx.x;
    int half = blk & 1, bch = blk >> 1;
    int h = bch & 31, c = (bch >> 5) & 7, b = bch >> 8;
    int t = threadIdx.x;
    int w = t >> 6, lane = t & 63;
    int quad = lane >> 4, l16 = lane & 15;
    size_t rowbase = (size_t)b * SEQ + c * CHUNK;

    // ---- absorbed cumsum: full-chunk scan (row = t) ----
    {
        int rid = (b * SEQ + c * CHUNK + t) * 32 + h;
        float s = part[rid] + part[131072 + rid] + part[262144 + rid] + part[393216 + rid];
        float dt_l = softplusf(s + dt_b[h] + dt_bias[h]);
        float A = -expf(A_log[h]);
        float v = dt_l * A;
        #pragma unroll
        for (int off = 1; off < 64; off <<= 1) {
            float u = __shfl_up(v, off);
            if (lane >= off) v += u;
        }
        if (lane == 63) wsum[w] = v;
        __syncthreads();
        float pre = 0.f;
        #pragma unroll
        for (int i = 0; i < 3; ++i)
            if (i < w) pre += wsum[i];
        float cum = v + pre;
        float tot = wsum[0] + wsum[1] + wsum[2] + wsum[3];
        sWv[t] = expf(tot - cum) * dt_l;
        if ((t >> 7) == half) {      // each half-block writes its own rows once
            size_t o = (size_t)bch * CHUNK + t;
            cumc[o] = cum;
            dtc[o] = dt_l;
        }
        if (half == 1 && t == 255) cd[bch] = expf(tot);
    }
    __syncthreads();

    int rowl = t >> 2;             // 0..63 row within tile
    int q4 = (t & 3) * 16;         // 16-col group

    f32x4 acc[4];
    #pragma unroll
    for (int nt = 0; nt < 4; ++nt) acc[nt] = (f32x4){0.f, 0.f, 0.f, 0.f};

    for (int tt = 0; tt < 2; ++tt) {
        int r0 = half * 128 + tt * 64;
        size_t grow = (rowbase + r0 + rowl) * NH + h;
        {   // stage khat^T: 16 cols of one k-row; invB via 4-lane reduce
            const float4* kp = (const float4*)(kst + grow * 64 + q4);
            float4 k0 = kp[0], k1 = kp[1], k2 = kp[2], k3 = kp[3];
            float ssq = k0.x*k0.x + k0.y*k0.y + k0.z*k0.z + k0.w*k0.w
                      + k1.x*k1.x + k1.y*k1.y + k1.z*k1.z + k1.w*k1.w
                      + k2.x*k2.x + k2.y*k2.y + k2.z*k2.z + k2.w*k2.w
                      + k3.x*k3.x + k3.y*k3.y + k3.z*k3.z + k3.w*k3.w;
            ssq += __shfl_xor(ssq, 1);
            ssq += __shfl_xor(ssq, 2);
            float ib = 1.f / fmaxf(sqrtf(ssq), 1e-12f);
            uint u0 = packbf2(k0.x*ib, k0.y*ib), u1 = packbf2(k0.z*ib, k0.w*ib);
            uint u2 = packbf2(k1.x*ib, k1.y*ib), u3 = packbf2(k1.z*ib, k1.w*ib);
            uint u4 = packbf2(k2.x*ib, k2.y*ib), u5 = packbf2(k2.z*ib, k2.w*ib);
            uint u6 = packbf2(k3.x*ib, k3.y*ib), u7 = packbf2(k3.z*ib, k3.w*ib);
            kT[(q4+ 0)*PST + rowl] = (short)u0; kT[(q4+ 1)*PST + rowl] = (short)(u0>>16);
            kT[(q4+ 2)*PST + rowl] = (short)u1; kT[(q4+ 3)*PST + rowl] = (short)(u1>>16);
            kT[(q4+ 4)*PST + rowl] = (short)u2; kT[(q4+ 5)*PST + rowl] = (short)(u2>>16);
            kT[(q4+ 6)*PST + rowl] = (short)u3; kT[(q4+ 7)*PST + rowl] = (short)(u3>>16);
            kT[(q4+ 8)*PST + rowl] = (short)u4; kT[(q4+ 9)*PST + rowl] = (short)(u4>>16);
            kT[(q4+10)*PST + rowl] = (short)u5; kT[(q4+11)*PST + rowl] = (short)(u5>>16);
            kT[(q4+12)*PST + rowl] = (short)u6; kT[(q4+13)*PST + rowl] = (short)(u6>>16);
            kT[(q4+14)*PST + rowl] = (short)u7; kT[(q4+15)*PST + rowl] = (short)(u7>>16);
        }
        {   // stage (x*wv)^T
            const float4* xp = (const float4*)(vst + grow * 64 + q4);
            float4 x0 = xp[0], x1 = xp[1], x2 = xp[2], x3 = xp[3];
            float wv = sWv[r0 + rowl];
            uint u0 = packbf2(x0.x*wv, x0.y*wv), u1 = packbf2(x0.z*wv, x0.w*wv);
            uint u2 = packbf2(x1.x*wv, x1.y*wv), u3 = packbf2(x1.z*wv, x1.w*wv);
            uint u4 = packbf2(x2.x*wv, x2.y*wv), u5 = packbf2(x2.z*wv, x2.w*wv);
            uint u6 = packbf2(x3.x*wv, x3.y*wv), u7 = packbf2(x3.z*wv, x3.w*wv);
            xwT[(q4+ 0)*PST + rowl] = (short)u0; xwT[(q4+ 1)*PST + rowl] = (short)(u0>>16);
            xwT[(q4+ 2)*PST + rowl] = (short)u1; xwT[(q4+ 3)*PST + rowl] = (short)(u1>>16);
            xwT[(q4+ 4)*PST + rowl] = (short)u2; xwT[(q4+ 5)*PST + rowl] = (short)(u2>>16);
            xwT[(q4+ 6)*PST + rowl] = (short)u3; xwT[(q4+ 7)*PST + rowl] = (short)(u3>>16);
            xwT[(q4+ 8)*PST + rowl] = (short)u4; xwT[(q4+ 9)*PST + rowl] = (short)(u4>>16);
            xwT[(q4+10)*PST + rowl] = (short)u5; xwT[(q4+11)*PST + rowl] = (short)(u5>>16);
            xwT[(q4+12)*PST + rowl] = (short)u6; xwT[(q4+13)*PST + rowl] = (short)(u6>>16);
            xwT[(q4+14)*PST + rowl] = (short)u7; xwT[(q4+15)*PST + rowl] = (short)(u7>>16);
        }
        __syncthreads();

        #pragma unroll
        for (int ks = 0; ks < 2; ++ks) {
            bf16x8 a = *(const bf16x8*)(xwT + (w*16 + l16)*PST + ks*32 + quad*8);
            #pragma unroll
            for (int nt = 0; nt < 4; ++nt) {
                bf16x8 bb = *(const bf16x8*)(kT + (nt*16 + l16)*PST + ks*32 + quad*8);
                acc[nt] = MFMA(a, bb, acc[nt]);
            }
        }
        __syncthreads();
    }

    size_t obase = (size_t)blk * 4096;
    #pragma unroll
    for (int nt = 0; nt < 4; ++nt)
        #pragma unroll
        for (int r = 0; r < 4; ++r)
            sp[obase + (w*16 + quad*4 + r) * 64 + nt*16 + l16] = acc[nt][r];
}

// ---------------------------------------------------------------------------
// K5: inter-chunk scan
// ---------------------------------------------------------------------------
__global__ __launch_bounds__(256) void k_scan(
    const float* __restrict__ sp, const float* __restrict__ cd,
    float* __restrict__ Hp)
{
    size_t id = (size_t)blockIdx.x * 256 + threadIdx.x;
    size_t bh = id >> 12, pn = id & 4095;
    size_t b = bh >> 5, h = bh & 31;
    float carry = 0.f;
    for (int c = 0; c < NCH; ++c) {
        size_t bch = (b * NCH + c) * NH + h;
        float st = sp[(bch * 2) * 4096 + pn] + sp[(bch * 2 + 1) * 4096 + pn];
        Hp[bch * 4096 + pn] = carry;
        carry = cd[bch] * carry + st;
    }
}

// ---------------------------------------------------------------------------
// K6: MFMA intra-chunk + H_prev (R9 structure, unchanged — best of 6
// variants; cvt_pk packing).
// ---------------------------------------------------------------------------
__global__ __launch_bounds__(256, 2) void k_intra(
    const float* __restrict__ qst, const float* __restrict__ kst,
    const float* __restrict__ vst,
    const float* __restrict__ cumc, const float* __restrict__ dtc,
    const float* __restrict__ Hp,
    short* __restrict__ ygb)
{
    __shared__ __align__(16) short B_s[2][64 * PST];
    __shared__ __align__(16) short XT_s[2][64 * PST];
    __shared__ __align__(16) short P_s[4 * 32 * PST];
    __shared__ float sCum[256];
    __shared__ float sDt[256];

    int bch = blockIdx.x;
    int h = bch & 31, c = (bch >> 5) & 7, b = bch >> 8;
    int t = threadIdx.x;
    int w = t >> 6, lane = t & 63;
    int quad = lane >> 4, l16 = lane & 15;
    size_t rowbase = (size_t)b * SEQ + c * CHUNK;

    sCum[t] = cumc[(size_t)bch * CHUNK + t];
    sDt[t]  = dtc[(size_t)bch * CHUNK + t];

    // staging thread mapping (constant across st)
    int ssA = t >> 2, q4A = (t & 3) * 16;      // B_s: row ssA, 16-col group
    int ss2 = t & 31, p0 = (t >> 5) * 8;       // XT: rows 2*ss2(+1), 8 p's

    // prefetch k/v for st=0 (flies under the Q/Hp prologue)
    float4 kv[4], xa[2], xb[2];
    {
        size_t gK = (rowbase + ssA) * NH + h;
        const float4* kp = (const float4*)(kst + gK * 64 + q4A);
        kv[0] = kp[0]; kv[1] = kp[1]; kv[2] = kp[2]; kv[3] = kp[3];
        size_t g0 = (rowbase + 2 * ss2) * NH + h;
        const float* vp0 = vst + g0 * 64 + p0;
        const float* vp1 = vst + (g0 + NH) * 64 + p0;
        xa[0] = *(const float4*)vp0; xa[1] = *(const float4*)(vp0 + 4);
        xb[0] = *(const float4*)vp1; xb[1] = *(const float4*)(vp1 + 4);
    }

    bf16x8 cf[2][2][2];
    #pragma unroll
    for (int is = 0; is < 2; ++is) {
        int strip = is ? (7 - w) : w;
        #pragma unroll
        for (int lt = 0; lt < 2; ++lt) {
            int l = strip * 32 + lt * 16 + l16;
            size_t grow = (rowbase + l) * NH + h;
            const float* qp = qst + grow * 64 + quad * 8;
            float4 a  = *(const float4*)qp;
            float4 bq = *(const float4*)(qp + 4);
            float4 c2 = *(const float4*)(qp + 32);
            float4 d  = *(const float4*)(qp + 36);
            float ssq = a.x*a.x + a.y*a.y + a.z*a.z + a.w*a.w
                      + bq.x*bq.x + bq.y*bq.y + bq.z*bq.z + bq.w*bq.w
                      + c2.x*c2.x + c2.y*c2.y + c2.z*c2.z + c2.w*c2.w
                      + d.x*d.x + d.y*d.y + d.z*d.z + d.w*d.w;
            ssq += __shfl_xor(ssq, 16);
            ssq += __shfl_xor(ssq, 32);
            float ic = 1.f / fmaxf(sqrtf(ssq), 1e-12f);
            cf[is][lt][0] = cvt8(a, bq, ic);
            cf[is][lt][1] = cvt8(c2, d, ic);
        }
    }

    f32x4 acc[2][2][4];
    #pragma unroll
    for (int is = 0; is < 2; ++is)
        #pragma unroll
        for (int lt = 0; lt < 2; ++lt)
            #pragma unroll
            for (int pt = 0; pt < 4; ++pt)
                acc[is][lt][pt] = (f32x4){0.f, 0.f, 0.f, 0.f};

    {
        bf16x8 hf[4][2];
        #pragma unroll
        for (int pt = 0; pt < 4; ++pt) {
            const float* hp = Hp + (size_t)bch * 4096 + (pt * 16 + l16) * 64 + quad * 8;
            hf[pt][0] = load_cvt8(hp, 1.f);
            hf[pt][1] = load_cvt8(hp + 32, 1.f);
        }
        #pragma unroll
        for (int is = 0; is < 2; ++is)
            #pragma unroll
            for (int lt = 0; lt < 2; ++lt)
                #pragma unroll
                for (int pt = 0; pt < 4; ++pt) {
                    acc[is][lt][pt] = MFMA(cf[is][lt][0], hf[pt][0], acc[is][lt][pt]);
                    acc[is][lt][pt] = MFMA(cf[is][lt][1], hf[pt][1], acc[is][lt][pt]);
                }
    }
    __syncthreads();   // sCum/sDt now visible to all waves
    #pragma unroll
    for (int is = 0; is < 2; ++is) {
        int strip = is ? (7 - w) : w;
        #pragma unroll
        for (int lt = 0; lt < 2; ++lt) {
            float e[4];
            #pragma unroll
            for (int r = 0; r < 4; ++r)
                e[r] = __expf(sCum[strip * 32 + lt * 16 + quad * 4 + r]);
            #pragma unroll
            for (int pt = 0; pt < 4; ++pt)
                #pragma unroll
                for (int r = 0; r < 4; ++r)
                    acc[is][lt][pt][r] *= e[r];
        }
    }

    short* Pw = P_s + w * 32 * PST;

    #pragma unroll
    for (int st = 0; st < 4; ++st) {
        // issue next-tile global loads first (hide under pack+barrier+compute)
        float4 kvN[4], xaN[2], xbN[2];
        if (st < 3) {
            size_t gK = (rowbase + (st + 1) * 64 + ssA) * NH + h;
            const float4* kp = (const float4*)(kst + gK * 64 + q4A);
            kvN[0] = kp[0]; kvN[1] = kp[1]; kvN[2] = kp[2]; kvN[3] = kp[3];
            size_t g0 = (rowbase + (st + 1) * 64 + 2 * ss2) * NH + h;
            const float* vp0 = vst + g0 * 64 + p0;
            const float* vp1 = vst + (g0 + NH) * 64 + p0;
            xaN[0] = *(const float4*)vp0; xaN[1] = *(const float4*)(vp0 + 4);
            xbN[0] = *(const float4*)vp1; xbN[1] = *(const float4*)(vp1 + 4);
        }

        short* Bb = B_s[st & 1];
        short* Xb = XT_s[st & 1];
        {   // pack K-hat (bf16) into Bb from regs
            float ssq = kv[0].x*kv[0].x + kv[0].y*kv[0].y + kv[0].z*kv[0].z + kv[0].w*kv[0].w
                      + kv[1].x*kv[1].x + kv[1].y*kv[1].y + kv[1].z*kv[1].z + kv[1].w*kv[1].w
                      + kv[2].x*kv[2].x + kv[2].y*kv[2].y + kv[2].z*kv[2].z + kv[2].w*kv[2].w
                      + kv[3].x*kv[3].x + kv[3].y*kv[3].y + kv[3].z*kv[3].z + kv[3].w*kv[3].w;
            ssq += __shfl_xor(ssq, 1);
            ssq += __shfl_xor(ssq, 2);
            float ib = 1.f / fmaxf(sqrtf(ssq), 1e-12f);
            uint u[8];
            u[0] = packbf2(kv[0].x * ib, kv[0].y * ib); u[1] = packbf2(kv[0].z * ib, kv[0].w * ib);
            u[2] = packbf2(kv[1].x * ib, kv[1].y * ib); u[3] = packbf2(kv[1].z * ib, kv[1].w * ib);
            u[4] = packbf2(kv[2].x * ib, kv[2].y * ib); u[5] = packbf2(kv[2].z * ib, kv[2].w * ib);
            u[6] = packbf2(kv[3].x * ib, kv[3].y * ib); u[7] = packbf2(kv[3].z * ib, kv[3].w * ib);
            uint* dst = (uint*)(Bb + ssA * PST + q4A);
            *(uint4*)dst = make_uint4(u[0], u[1], u[2], u[3]);
            *(uint4*)(dst + 4) = make_uint4(u[4], u[5], u[6], u[7]);
        }
        {   // pack dt-scaled X^T (bf16 pair-packed) into Xb from regs
            float dt0 = sDt[st * 64 + 2 * ss2];
            float dt1 = sDt[st * 64 + 2 * ss2 + 1];
            float x0[8] = {xa[0].x, xa[0].y, xa[0].z, xa[0].w,
                           xa[1].x, xa[1].y, xa[1].z, xa[1].w};
            float x1[8] = {xb[0].x, xb[0].y, xb[0].z, xb[0].w,
                           xb[1].x, xb[1].y, xb[1].z, xb[1].w};
            uint* xt = (uint*)Xb;
            #pragma unroll
            for (int i = 0; i < 8; ++i)
                xt[(p0 + i) * (PST / 2) + ss2] = packbf2(x0[i] * dt0, x1[i] * dt1);
        }
        __syncthreads();

        bf16x8 xf[4][2];
        #pragma unroll
        for (int pt = 0; pt < 4; ++pt) {
            #pragma unroll
            for (int ks = 0; ks < 2; ++ks)
                xf[pt][ks] = *(const bf16x8*)(Xb + (pt * 16 + l16) * PST + ks * 32 + quad * 8);
        }

        #pragma unroll
        for (int is = 0; is < 2; ++is) {
            int strip = is ? (7 - w) : w;
            int L0 = strip * 32;
            if (L0 + 31 < st * 64) continue;

            #pragma unroll
            for (int lt = 0; lt < 2; ++lt) {
                int Lt = L0 + lt * 16;
                float cl = sCum[Lt + l16];
                int lrow = lt * 16 + l16;
                #pragma unroll
                for (int mt = 0; mt < 4; ++mt) {
                    int S0 = st * 64 + mt * 16;
                    uint* pdst = (uint*)(Pw + lrow * PST + mt * 16 + quad * 4);
                    if (S0 > Lt + 15) {
                        *(uint2*)pdst = make_uint2(0u, 0u);
                        continue;
                    }
                    f32x4 sa = (f32x4){0.f, 0.f, 0.f, 0.f};
                    bf16x8 af0 = *(const bf16x8*)(Bb + (mt * 16 + l16) * PST + quad * 8);
                    bf16x8 af1 = *(const bf16x8*)(Bb + (mt * 16 + l16) * PST + 32 + quad * 8);
                    sa = MFMA(af0, cf[is][lt][0], sa);
                    sa = MFMA(af1, cf[is][lt][1], sa);
                    float vals[4];
                    #pragma unroll
                    for (int r = 0; r < 4; ++r) {
                        int s = S0 + quad * 4 + r;
                        float v = sa[r] * __expf(cl - sCum[s]);
                        vals[r] = (Lt + l16 >= s) ? v : 0.f;
                    }
                    *(uint2*)pdst = make_uint2(packbf2(vals[0], vals[1]),
                                               packbf2(vals[2], vals[3]));
                }
            }
            #pragma unroll
            for (int lt = 0; lt < 2; ++lt) {
                int Lmax = L0 + lt * 16 + 15;
                #pragma unroll
                for (int ks = 0; ks < 2; ++ks) {
                    if (st * 64 + ks * 32 > Lmax) continue;
                    bf16x8 af = *(const bf16x8*)(Pw + (lt * 16 + l16) * PST + ks * 32 + quad * 8);
                    #pragma unroll
                    for (int pt = 0; pt < 4; ++pt)
                        acc[is][lt][pt] = MFMA(af, xf[pt][ks], acc[is][lt][pt]);
                }
            }
        }

        if (st < 3) {
            kv[0] = kvN[0]; kv[1] = kvN[1]; kv[2] = kvN[2]; kv[3] = kvN[3];
            xa[0] = xaN[0]; xa[1] = xaN[1];
            xb[0] = xbN[0]; xb[1] = xbN[1];
        }
    }

    #pragma unroll
    for (int is = 0; is < 2; ++is) {
        int strip = is ? (7 - w) : w;
        #pragma unroll
        for (int lt = 0; lt < 2; ++lt)
            #pragma unroll
            for (int pt = 0; pt < 4; ++pt)
                #pragma unroll
                for (int r = 0; r < 4; ++r) {
                    int l = strip * 32 + lt * 16 + quad * 4 + r;
                    int p = pt * 16 + l16;
                    ygb[((rowbase + l) * NH + h) * 64 + p] = f2bf(acc[is][lt][pt][r]);
                }
    }
}

// ---------------------------------------------------------------------------
// K7: fused gate + RMSNorm + per-head o_proj.
// ---------------------------------------------------------------------------
__global__ __launch_bounds__(256) void k_out(
    const short* __restrict__ ygb, const float* __restrict__ part,
    const float* __restrict__ g_b, const short* __restrict__ nwWT,
    const float* __restrict__ o_b, float* __restrict__ out)
{
    __shared__ __align__(16) short yS[16 * 1024];   // 16 rows x own head-half
    __shared__ float silS[16 * 32];
    __shared__ float scaleS[16];
    int blk = blockIdx.x;
    int half = blk & 1, rt = blk >> 1;
    int r0 = rt * 16;
    int t = threadIdx.x;
    int w = t >> 6, lane = t & 63, quad = lane >> 4, l16 = lane & 15;

    // phase 0: gates (sum g split-K partials + bias, silu) for all 32 heads
    const float* gpart = part + 4 * 131072;
    #pragma unroll
    for (int ii = 0; ii < 2; ++ii) {
        int idx = t + ii * 256;                 // (row 0..15, h 0..31)
        int rr = idx >> 5, hh = idx & 31;
        int rid = (r0 + rr) * 32 + hh;
        float g = gpart[rid] + gpart[131072 + rid] + gpart[262144 + rid]
                + gpart[393216 + rid] + g_b[hh];
        silS[idx] = g / (1.f + expf(-g));
    }
    __syncthreads();

    // phase 1: stream full rows, gated sumsq; stash own half to LDS (swizzled)
    int r = t >> 4, cl = t & 15;
    const char* yrow = (const char*)(ygb + (size_t)(r0 + r) * 2048);
    float ssq = 0.f;
    #pragma unroll
    for (int i = 0; i < 16; ++i) {
        int cb = i * 256 + cl * 16;             // byte offset 0..4095
        uint4 u = *(const uint4*)(yrow + cb);
        float s = silS[r * 32 + (cb >> 7)];
        float v0 = bf2f((ushort)(u.x & 0xFFFF)) * s, v1 = bf2f((ushort)(u.x >> 16)) * s;
        float v2 = bf2f((ushort)(u.y & 0xFFFF)) * s, v3 = bf2f((ushort)(u.y >> 16)) * s;
        float v4 = bf2f((ushort)(u.z & 0xFFFF)) * s, v5 = bf2f((ushort)(u.z >> 16)) * s;
        float v6 = bf2f((ushort)(u.w & 0xFFFF)) * s, v7 = bf2f((ushort)(u.w >> 16)) * s;
        ssq += v0*v0 + v1*v1 + v2*v2 + v3*v3 + v4*v4 + v5*v5 + v6*v6 + v7*v7;
        if ((cb >> 11) == half) {
            int cbl = cb & 2047;
            *(uint4*)((char*)yS + r * 2048 + (cbl ^ ((r & 7) << 4))) = u;
        }
    }
    ssq += __shfl_xor(ssq, 1); ssq += __shfl_xor(ssq, 2);
    ssq += __shfl_xor(ssq, 4); ssq += __shfl_xor(ssq, 8);
    if (cl == 0) scaleS[r] = rsqrtf(ssq / 2048.f + 1e-5f);
    __syncthreads();

    // phase 2: wave w handles 4 heads of its half
    #pragma unroll
    for (int hh = 0; hh < 4; ++hh) {
        int h = half * 16 + w * 4 + hh;
        int hl = h & 15;
        const short* wb = nwWT + (size_t)h * 4096;
        bf16x8 bfr[4][2];
        #pragma unroll
        for (int nt = 0; nt < 4; ++nt)
            #pragma unroll
            for (int ks = 0; ks < 2; ++ks)
                bfr[nt][ks] = *(const bf16x8*)(wb + (nt * 16 + l16) * 64 + ks * 32 + quad * 8);
        bf16x8 af[2];
        #pragma unroll
        for (int ks = 0; ks < 2; ++ks) {
            int cbl = hl * 128 + ks * 64 + quad * 16;
            af[ks] = *(const bf16x8*)((const char*)yS + l16 * 2048 + (cbl ^ ((l16 & 7) << 4)));
        }
        f32x4 acc[4];
        #pragma unroll
        for (int nt = 0; nt < 4; ++nt) acc[nt] = (f32x4){0.f, 0.f, 0.f, 0.f};
        #pragma unroll
        for (int ks = 0; ks < 2; ++ks)
            #pragma unroll
            for (int nt = 0; nt < 4; ++nt)
                acc[nt] = MFMA(af[ks], bfr[nt][ks], acc[nt]);
        #pragma unroll
        for (int nt = 0; nt < 4; ++nt) {
            float bv = o_b[h * 64 + nt * 16 + l16];
            #pragma unroll
            for (int rr = 0; rr < 4; ++rr) {
                int row = quad * 4 + rr;
                float o = acc[nt][rr] * silS[row * 32 + h] * scaleS[row] + bv;
                out[(size_t)(r0 + row) * 2048 + h * 64 + nt * 16 + l16] = o;
            }
        }
    }
}

extern "C" void kernel_launch(void* const* d_in, const int* in_sizes, int n_in,
                              void* d_out, int out_size, void* d_ws, size_t ws_size,
                              hipStream_t stream) {
    const float* hs_ab   = (const float*)d_in[0];
    const float* hs_g    = (const float*)d_in[1];
    const float* qst     = (const float*)d_in[2];
    const float* kst     = (const float*)d_in[3];
    const float* vst     = (const float*)d_in[4];
    const float* dt_w    = (const float*)d_in[5];
    const float* dt_b    = (const float*)d_in[6];
    const float* g_w     = (const float*)d_in[7];
    const float* g_b     = (const float*)d_in[8];
    const float* A_log   = (const float*)d_in[9];
    const float* dt_bias = (const float*)d_in[10];
    const float* norm_w  = (const float*)d_in[11];
    const float* o_w     = (const float*)d_in[12];
    const float* o_b     = (const float*)d_in[13];
    float* out = (float*)d_out;

    float* ws = (float*)d_ws;
    size_t off = 0;
    float* part   = ws + off; off += (size_t)2 * KSPLIT * 4096 * 32;  // 1M floats
    float* cumc   = ws + off; off += (size_t)NBCH * CHUNK;
    float* dtc    = ws + off; off += (size_t)NBCH * CHUNK;
    float* cd_ws  = ws + off; off += (size_t)NBCH;
    float* sp     = ws + off; off += (size_t)NBCH * 2 * 4096;
    float* Hp     = ws + off; off += (size_t)NBCH * 4096;
    short* nwWT   = (short*)(ws + off); off += (size_t)NH * 64 * 64 / 2;  // 131072 shorts

    short* ygb = (short*)sp;   // aliases sp (sp fully consumed by k_scan)

    k_proj<<<2 * KSPLIT * (BATCH * SEQ / 32) + NH, 256, 0, stream>>>(
        hs_ab, hs_g, dt_w, g_w, o_w, norm_w, part, nwWT);
    k_states<<<NBCH * 2, 256, 0, stream>>>(part, dt_b, dt_bias, A_log,
                                           kst, vst, cumc, dtc, cd_ws, sp);
    k_scan<<<BATCH * NH * 4096 / 256, 256, 0, stream>>>(sp, cd_ws, Hp);
    k_intra<<<NBCH, 256, 0, stream>>>(qst, kst, vst, cumc, dtc, Hp, ygb);
    k_out<<<2 * (BATCH * SEQ / 16), 256, 0, stream>>>(ygb, part, g_b, nwWT, o_b, out);
}

// Round 11
// 257.700 us; speedup vs baseline: 1.0854x; 1.0108x over previous
//
#include <hip/hip_runtime.h>
#include <math.h>

#define BATCH 2
#define SEQ   2048
#define NH    32
#define HID   2048
#define CHUNK 256
#define NCH   8
#define NBCH  (BATCH*NCH*NH)   // 512
#define PST   72               // padded bf16 LDS leading dim (b128-alignable)
#define BK    256
#define APST  264              // BK+8 shorts; row stride 528 B = 33*16 (b128-aligned)
#define KSPLIT 4
#define KSEG  (HID / KSPLIT)   // 512

typedef __attribute__((ext_vector_type(4))) float f32x4;
typedef __attribute__((ext_vector_type(8))) short bf16x8;
typedef unsigned int uint;
typedef unsigned short ushort;

__device__ __forceinline__ float softplusf(float x) {
    return x > 20.f ? x : log1pf(expf(x));
}

// HW packed f32->bf16 RNE (1 VALU op; bit-identical to manual round, R9).
__device__ __forceinline__ uint packbf2(float lo, float hi) {
    uint r;
    asm("v_cvt_pk_bf16_f32 %0, %1, %2" : "=v"(r) : "v"(lo), "v"(hi));
    return r;
}
__device__ __forceinline__ short f2bf(float f) {
    return (short)packbf2(f, 0.f);
}
__device__ __forceinline__ float bf2f(ushort s) {
    union { uint u; float f; } v; v.u = ((uint)s) << 16; return v.f;
}

__device__ __forceinline__ bf16x8 load_cvt8(const float* p, float scale) {
    float4 a = *(const float4*)p;
    float4 b = *(const float4*)(p + 4);
    union { bf16x8 v; uint u[4]; } r;
    r.u[0] = packbf2(a.x * scale, a.y * scale);
    r.u[1] = packbf2(a.z * scale, a.w * scale);
    r.u[2] = packbf2(b.x * scale, b.y * scale);
    r.u[3] = packbf2(b.z * scale, b.w * scale);
    return r.v;
}

__device__ __forceinline__ bf16x8 cvt8(float4 a, float4 b, float s) {
    union { bf16x8 v; uint u[4]; } r;
    r.u[0] = packbf2(a.x * s, a.y * s);
    r.u[1] = packbf2(a.z * s, a.w * s);
    r.u[2] = packbf2(b.x * s, b.y * s);
    r.u[3] = packbf2(b.z * s, b.w * s);
    return r.v;
}

#define MFMA(a,b,c) __builtin_amdgcn_mfma_f32_16x16x32_bf16((a),(b),(c),0,0,0)

// ---------------------------------------------------------------------------
// K1: dt/g projections as bf16 MFMA GEMM (split-K by 4), plus 32 trailing
// blocks that build nwWT[h][q][p] = bf16(o_w[h][p][q] * norm_w[h*64+p]).
// ---------------------------------------------------------------------------
__global__ __launch_bounds__(256) void k_proj(
    const float* __restrict__ hs_ab, const float* __restrict__ hs_g,
    const float* __restrict__ dt_w, const float* __restrict__ g_w,
    const float* __restrict__ o_w,  const float* __restrict__ norm_w,
    float* __restrict__ part, short* __restrict__ nwWT)
{
    __shared__ __align__(16) short As[32 * APST];
    __shared__ __align__(16) short Bs[32 * APST];
    int blk = blockIdx.x;
    int t = threadIdx.x;

    if (blk >= 2 * KSPLIT * 128) {
        // --- weight prep: transpose o_w per head, fold norm_w, cast bf16 ---
        int h = blk - 2 * KSPLIT * 128;
        float* tile = (float*)As;   // 64x64 f32 = 16 KB
        {
            int p = t >> 2, q0 = (t & 3) * 16;
            const float* wp = o_w + (size_t)h * 4096 + p * 64 + q0;
            #pragma unroll
            for (int i = 0; i < 4; ++i)
                *(float4*)(tile + p * 64 + q0 + i * 4) = *(const float4*)(wp + i * 4);
        }
        __syncthreads();
        int q = t >> 2, p0 = (t & 3) * 16;
        uint us[8];
        #pragma unroll
        for (int j = 0; j < 8; ++j) {
            float lo = tile[(p0 + 2*j    ) * 64 + q] * norm_w[h * 64 + p0 + 2*j];
            float hi = tile[(p0 + 2*j + 1) * 64 + q] * norm_w[h * 64 + p0 + 2*j + 1];
            us[j] = packbf2(lo, hi);
        }
        uint* dst = (uint*)(nwWT + (size_t)h * 4096 + q * 64 + p0);
        *(uint4*)dst       = make_uint4(us[0], us[1], us[2], us[3]);
        *(uint4*)(dst + 4) = make_uint4(us[4], us[5], us[6], us[7]);
        return;
    }

    int ksp = blk >> 8;          // 0..3 : K segment
    int rem = blk & 255;
    int which = rem >> 7;        // 0..1 : ab vs g
    int rt = rem & 127;          // 0..127 : 32-row tile
    int r0 = rt * 32;
    const float* Am = which ? hs_g : hs_ab;
    const float* W  = which ? g_w  : dt_w;
    int w = t >> 6, lane = t & 63, quad = lane >> 4, l16 = lane & 15;
    int mh = w & 1, nh = w >> 1;

    f32x4 acc = (f32x4){0.f, 0.f, 0.f, 0.f};

    for (int kc = ksp * KSEG; kc < ksp * KSEG + KSEG; kc += BK) {
        __syncthreads();
        {   // stage A: 32 rows x BK cols, bf16-packed
            int row = t >> 3, k0 = (t & 7) * 32;
            const float* src = Am + (size_t)(r0 + row) * HID + kc + k0;
            uint* dst = (uint*)(As + row * APST + k0);
            #pragma unroll
            for (int i = 0; i < 4; ++i) {
                float4 a = *(const float4*)(src + i * 8);
                float4 b = *(const float4*)(src + i * 8 + 4);
                dst[i*4+0] = packbf2(a.x, a.y); dst[i*4+1] = packbf2(a.z, a.w);
                dst[i*4+2] = packbf2(b.x, b.y); dst[i*4+3] = packbf2(b.z, b.w);
            }
        }
        if (t < 128) {   // stage W transposed: Bs[n][k] = W[kc+k][n], pair-packed
            int k2 = t * 2;
            const float* w0 = W + (size_t)(kc + k2) * NH;
            const float* w1 = w0 + NH;
            #pragma unroll
            for (int n = 0; n < 32; n += 4) {
                float4 a = *(const float4*)(w0 + n);
                float4 b = *(const float4*)(w1 + n);
                *((uint*)(Bs + (n+0) * APST + k2)) = packbf2(a.x, b.x);
                *((uint*)(Bs + (n+1) * APST + k2)) = packbf2(a.y, b.y);
                *((uint*)(Bs + (n+2) * APST + k2)) = packbf2(a.z, b.z);
                *((uint*)(Bs + (n+3) * APST + k2)) = packbf2(a.w, b.w);
            }
        }
        __syncthreads();
        #pragma unroll
        for (int ks = 0; ks < BK / 32; ++ks) {
            bf16x8 af = *(const bf16x8*)(As + (mh*16 + l16) * APST + ks*32 + quad*8);
            bf16x8 bf = *(const bf16x8*)(Bs + (nh*16 + l16) * APST + ks*32 + quad*8);
            acc = MFMA(af, bf, acc);
        }
    }

    int n = nh * 16 + l16;
    int Rb = r0 + mh * 16 + quad * 4;
    float* pd = part + ((size_t)(which * KSPLIT + ksp) * 4096 + Rb) * 32 + n;
    #pragma unroll
    for (int r = 0; r < 4; ++r)
        pd[r * 32] = acc[r];
}

// ---------------------------------------------------------------------------
// K4: chunk-state GEMM via MFMA with k_cumsum absorbed (R10). R11: states
// stored bf16 (sp traffic halved; carry recurrence inputs were already
// bf16-rounded products).
// ---------------------------------------------------------------------------
__global__ __launch_bounds__(256) void k_states(
    const float* __restrict__ part, const float* __restrict__ dt_b,
    const float* __restrict__ dt_bias, const float* __restrict__ A_log,
    const float* __restrict__ kst, const float* __restrict__ vst,
    float* __restrict__ cumc, float* __restrict__ dtc, float* __restrict__ cd,
    short* __restrict__ sp)
{
    __shared__ __align__(16) short kT[64 * PST];    // khat^T  [n][s]
    __shared__ __align__(16) short xwT[64 * PST];   // (x*wv)^T [p][s]
    __shared__ float wsum[4];
    __shared__ float sWv[256];

    int blk = blockIdx.x;
    int half = blk & 1, bch = blk >> 1;
    int h = bch & 31, c = (bch >> 5) & 7, b = bch >> 8;
    int t = threadIdx.x;
    int w = t >> 6, lane = t & 63;
    int quad = lane >> 4, l16 = lane & 15;
    size_t rowbase = (size_t)b * SEQ + c * CHUNK;

    // ---- absorbed cumsum: full-chunk scan (row = t) ----
    {
        int rid = (b * SEQ + c * CHUNK + t) * 32 + h;
        float s = part[rid] + part[131072 + rid] + part[262144 + rid] + part[393216 + rid];
        float dt_l = softplusf(s + dt_b[h] + dt_bias[h]);
        float A = -expf(A_log[h]);
        float v = dt_l * A;
        #pragma unroll
        for (int off = 1; off < 64; off <<= 1) {
            float u = __shfl_up(v, off);
            if (lane >= off) v += u;
        }
        if (lane == 63) wsum[w] = v;
        __syncthreads();
        float pre = 0.f;
        #pragma unroll
        for (int i = 0; i < 3; ++i)
            if (i < w) pre += wsum[i];
        float cum = v + pre;
        float tot = wsum[0] + wsum[1] + wsum[2] + wsum[3];
        sWv[t] = expf(tot - cum) * dt_l;
        if ((t >> 7) == half) {      // each half-block writes its own rows once
            size_t o = (size_t)bch * CHUNK + t;
            cumc[o] = cum;
            dtc[o] = dt_l;
        }
        if (half == 1 && t == 255) cd[bch] = expf(tot);
    }
    __syncthreads();

    int rowl = t >> 2;             // 0..63 row within tile
    int q4 = (t & 3) * 16;         // 16-col group

    f32x4 acc[4];
    #pragma unroll
    for (int nt = 0; nt < 4; ++nt) acc[nt] = (f32x4){0.f, 0.f, 0.f, 0.f};

    for (int tt = 0; tt < 2; ++tt) {
        int r0 = half * 128 + tt * 64;
        size_t grow = (rowbase + r0 + rowl) * NH + h;
        {   // stage khat^T: 16 cols of one k-row; invB via 4-lane reduce
            const float4* kp = (const float4*)(kst + grow * 64 + q4);
            float4 k0 = kp[0], k1 = kp[1], k2 = kp[2], k3 = kp[3];
            float ssq = k0.x*k0.x + k0.y*k0.y + k0.z*k0.z + k0.w*k0.w
                      + k1.x*k1.x + k1.y*k1.y + k1.z*k1.z + k1.w*k1.w
                      + k2.x*k2.x + k2.y*k2.y + k2.z*k2.z + k2.w*k2.w
                      + k3.x*k3.x + k3.y*k3.y + k3.z*k3.z + k3.w*k3.w;
            ssq += __shfl_xor(ssq, 1);
            ssq += __shfl_xor(ssq, 2);
            float ib = 1.f / fmaxf(sqrtf(ssq), 1e-12f);
            uint u0 = packbf2(k0.x*ib, k0.y*ib), u1 = packbf2(k0.z*ib, k0.w*ib);
            uint u2 = packbf2(k1.x*ib, k1.y*ib), u3 = packbf2(k1.z*ib, k1.w*ib);
            uint u4 = packbf2(k2.x*ib, k2.y*ib), u5 = packbf2(k2.z*ib, k2.w*ib);
            uint u6 = packbf2(k3.x*ib, k3.y*ib), u7 = packbf2(k3.z*ib, k3.w*ib);
            kT[(q4+ 0)*PST + rowl] = (short)u0; kT[(q4+ 1)*PST + rowl] = (short)(u0>>16);
            kT[(q4+ 2)*PST + rowl] = (short)u1; kT[(q4+ 3)*PST + rowl] = (short)(u1>>16);
            kT[(q4+ 4)*PST + rowl] = (short)u2; kT[(q4+ 5)*PST + rowl] = (short)(u2>>16);
            kT[(q4+ 6)*PST + rowl] = (short)u3; kT[(q4+ 7)*PST + rowl] = (short)(u3>>16);
            kT[(q4+ 8)*PST + rowl] = (short)u4; kT[(q4+ 9)*PST + rowl] = (short)(u4>>16);
            kT[(q4+10)*PST + rowl] = (short)u5; kT[(q4+11)*PST + rowl] = (short)(u5>>16);
            kT[(q4+12)*PST + rowl] = (short)u6; kT[(q4+13)*PST + rowl] = (short)(u6>>16);
            kT[(q4+14)*PST + rowl] = (short)u7; kT[(q4+15)*PST + rowl] = (short)(u7>>16);
        }
        {   // stage (x*wv)^T
            const float4* xp = (const float4*)(vst + grow * 64 + q4);
            float4 x0 = xp[0], x1 = xp[1], x2 = xp[2], x3 = xp[3];
            float wv = sWv[r0 + rowl];
            uint u0 = packbf2(x0.x*wv, x0.y*wv), u1 = packbf2(x0.z*wv, x0.w*wv);
            uint u2 = packbf2(x1.x*wv, x1.y*wv), u3 = packbf2(x1.z*wv, x1.w*wv);
            uint u4 = packbf2(x2.x*wv, x2.y*wv), u5 = packbf2(x2.z*wv, x2.w*wv);
            uint u6 = packbf2(x3.x*wv, x3.y*wv), u7 = packbf2(x3.z*wv, x3.w*wv);
            xwT[(q4+ 0)*PST + rowl] = (short)u0; xwT[(q4+ 1)*PST + rowl] = (short)(u0>>16);
            xwT[(q4+ 2)*PST + rowl] = (short)u1; xwT[(q4+ 3)*PST + rowl] = (short)(u1>>16);
            xwT[(q4+ 4)*PST + rowl] = (short)u2; xwT[(q4+ 5)*PST + rowl] = (short)(u2>>16);
            xwT[(q4+ 6)*PST + rowl] = (short)u3; xwT[(q4+ 7)*PST + rowl] = (short)(u3>>16);
            xwT[(q4+ 8)*PST + rowl] = (short)u4; xwT[(q4+ 9)*PST + rowl] = (short)(u4>>16);
            xwT[(q4+10)*PST + rowl] = (short)u5; xwT[(q4+11)*PST + rowl] = (short)(u5>>16);
            xwT[(q4+12)*PST + rowl] = (short)u6; xwT[(q4+13)*PST + rowl] = (short)(u6>>16);
            xwT[(q4+14)*PST + rowl] = (short)u7; xwT[(q4+15)*PST + rowl] = (short)(u7>>16);
        }
        __syncthreads();

        #pragma unroll
        for (int ks = 0; ks < 2; ++ks) {
            bf16x8 a = *(const bf16x8*)(xwT + (w*16 + l16)*PST + ks*32 + quad*8);
            #pragma unroll
            for (int nt = 0; nt < 4; ++nt) {
                bf16x8 bb = *(const bf16x8*)(kT + (nt*16 + l16)*PST + ks*32 + quad*8);
                acc[nt] = MFMA(a, bb, acc[nt]);
            }
        }
        __syncthreads();
    }

    size_t obase = (size_t)blk * 4096;
    #pragma unroll
    for (int nt = 0; nt < 4; ++nt)
        #pragma unroll
        for (int r = 0; r < 4; ++r)
            sp[obase + (w*16 + quad*4 + r) * 64 + nt*16 + l16] = f2bf(acc[nt][r]);
}

// ---------------------------------------------------------------------------
// K5: inter-chunk scan. R11: bf16 in (states) / bf16 out (Hp). Carry stays
// f32 in-register; bf16(carry) at store is bit-identical to what k_intra's
// load-time rounding produced before.
// ---------------------------------------------------------------------------
__global__ __launch_bounds__(256) void k_scan(
    const short* __restrict__ sp, const float* __restrict__ cd,
    short* __restrict__ Hp)
{
    size_t id = (size_t)blockIdx.x * 256 + threadIdx.x;
    size_t bh = id >> 12, pn = id & 4095;
    size_t b = bh >> 5, h = bh & 31;
    float carry = 0.f;
    for (int c = 0; c < NCH; ++c) {
        size_t bch = (b * NCH + c) * NH + h;
        float st = bf2f((ushort)sp[(bch * 2) * 4096 + pn])
                 + bf2f((ushort)sp[(bch * 2 + 1) * 4096 + pn]);
        Hp[bch * 4096 + pn] = f2bf(carry);
        carry = cd[bch] * carry + st;
    }
}

// ---------------------------------------------------------------------------
// K6: MFMA intra-chunk + H_prev (R9 structure — best of 6 variants).
// R11: Hp consumed directly as bf16 fragments (no conversion).
// ---------------------------------------------------------------------------
__global__ __launch_bounds__(256, 2) void k_intra(
    const float* __restrict__ qst, const float* __restrict__ kst,
    const float* __restrict__ vst,
    const float* __restrict__ cumc, const float* __restrict__ dtc,
    const short* __restrict__ Hp,
    short* __restrict__ ygb)
{
    __shared__ __align__(16) short B_s[2][64 * PST];
    __shared__ __align__(16) short XT_s[2][64 * PST];
    __shared__ __align__(16) short P_s[4 * 32 * PST];
    __shared__ float sCum[256];
    __shared__ float sDt[256];

    int bch = blockIdx.x;
    int h = bch & 31, c = (bch >> 5) & 7, b = bch >> 8;
    int t = threadIdx.x;
    int w = t >> 6, lane = t & 63;
    int quad = lane >> 4, l16 = lane & 15;
    size_t rowbase = (size_t)b * SEQ + c * CHUNK;

    sCum[t] = cumc[(size_t)bch * CHUNK + t];
    sDt[t]  = dtc[(size_t)bch * CHUNK + t];

    // staging thread mapping (constant across st)
    int ssA = t >> 2, q4A = (t & 3) * 16;      // B_s: row ssA, 16-col group
    int ss2 = t & 31, p0 = (t >> 5) * 8;       // XT: rows 2*ss2(+1), 8 p's

    // prefetch k/v for st=0 (flies under the Q/Hp prologue)
    float4 kv[4], xa[2], xb[2];
    {
        size_t gK = (rowbase + ssA) * NH + h;
        const float4* kp = (const float4*)(kst + gK * 64 + q4A);
        kv[0] = kp[0]; kv[1] = kp[1]; kv[2] = kp[2]; kv[3] = kp[3];
        size_t g0 = (rowbase + 2 * ss2) * NH + h;
        const float* vp0 = vst + g0 * 64 + p0;
        const float* vp1 = vst + (g0 + NH) * 64 + p0;
        xa[0] = *(const float4*)vp0; xa[1] = *(const float4*)(vp0 + 4);
        xb[0] = *(const float4*)vp1; xb[1] = *(const float4*)(vp1 + 4);
    }

    bf16x8 cf[2][2][2];
    #pragma unroll
    for (int is = 0; is < 2; ++is) {
        int strip = is ? (7 - w) : w;
        #pragma unroll
        for (int lt = 0; lt < 2; ++lt) {
            int l = strip * 32 + lt * 16 + l16;
            size_t grow = (rowbase + l) * NH + h;
            const float* qp = qst + grow * 64 + quad * 8;
            float4 a  = *(const float4*)qp;
            float4 bq = *(const float4*)(qp + 4);
            float4 c2 = *(const float4*)(qp + 32);
            float4 d  = *(const float4*)(qp + 36);
            float ssq = a.x*a.x + a.y*a.y + a.z*a.z + a.w*a.w
                      + bq.x*bq.x + bq.y*bq.y + bq.z*bq.z + bq.w*bq.w
                      + c2.x*c2.x + c2.y*c2.y + c2.z*c2.z + c2.w*c2.w
                      + d.x*d.x + d.y*d.y + d.z*d.z + d.w*d.w;
            ssq += __shfl_xor(ssq, 16);
            ssq += __shfl_xor(ssq, 32);
            float ic = 1.f / fmaxf(sqrtf(ssq), 1e-12f);
            cf[is][lt][0] = cvt8(a, bq, ic);
            cf[is][lt][1] = cvt8(c2, d, ic);
        }
    }

    f32x4 acc[2][2][4];
    #pragma unroll
    for (int is = 0; is < 2; ++is)
        #pragma unroll
        for (int lt = 0; lt < 2; ++lt)
            #pragma unroll
            for (int pt = 0; pt < 4; ++pt)
                acc[is][lt][pt] = (f32x4){0.f, 0.f, 0.f, 0.f};

    {
        bf16x8 hf[4][2];
        #pragma unroll
        for (int pt = 0; pt < 4; ++pt) {
            const short* hp = Hp + (size_t)bch * 4096 + (pt * 16 + l16) * 64 + quad * 8;
            hf[pt][0] = *(const bf16x8*)hp;
            hf[pt][1] = *(const bf16x8*)(hp + 32);
        }
        #pragma unroll
        for (int is = 0; is < 2; ++is)
            #pragma unroll
            for (int lt = 0; lt < 2; ++lt)
                #pragma unroll
                for (int pt = 0; pt < 4; ++pt) {
                    acc[is][lt][pt] = MFMA(cf[is][lt][0], hf[pt][0], acc[is][lt][pt]);
                    acc[is][lt][pt] = MFMA(cf[is][lt][1], hf[pt][1], acc[is][lt][pt]);
                }
    }
    __syncthreads();   // sCum/sDt now visible to all waves
    #pragma unroll
    for (int is = 0; is < 2; ++is) {
        int strip = is ? (7 - w) : w;
        #pragma unroll
        for (int lt = 0; lt < 2; ++lt) {
            float e[4];
            #pragma unroll
            for (int r = 0; r < 4; ++r)
                e[r] = __expf(sCum[strip * 32 + lt * 16 + quad * 4 + r]);
            #pragma unroll
            for (int pt = 0; pt < 4; ++pt)
                #pragma unroll
                for (int r = 0; r < 4; ++r)
                    acc[is][lt][pt][r] *= e[r];
        }
    }

    short* Pw = P_s + w * 32 * PST;

    #pragma unroll
    for (int st = 0; st < 4; ++st) {
        // issue next-tile global loads first (hide under pack+barrier+compute)
        float4 kvN[4], xaN[2], xbN[2];
        if (st < 3) {
            size_t gK = (rowbase + (st + 1) * 64 + ssA) * NH + h;
            const float4* kp = (const float4*)(kst + gK * 64 + q4A);
            kvN[0] = kp[0]; kvN[1] = kp[1]; kvN[2] = kp[2]; kvN[3] = kp[3];
            size_t g0 = (rowbase + (st + 1) * 64 + 2 * ss2) * NH + h;
            const float* vp0 = vst + g0 * 64 + p0;
            const float* vp1 = vst + (g0 + NH) * 64 + p0;
            xaN[0] = *(const float4*)vp0; xaN[1] = *(const float4*)(vp0 + 4);
            xbN[0] = *(const float4*)vp1; xbN[1] = *(const float4*)(vp1 + 4);
        }

        short* Bb = B_s[st & 1];
        short* Xb = XT_s[st & 1];
        {   // pack K-hat (bf16) into Bb from regs
            float ssq = kv[0].x*kv[0].x + kv[0].y*kv[0].y + kv[0].z*kv[0].z + kv[0].w*kv[0].w
                      + kv[1].x*kv[1].x + kv[1].y*kv[1].y + kv[1].z*kv[1].z + kv[1].w*kv[1].w
                      + kv[2].x*kv[2].x + kv[2].y*kv[2].y + kv[2].z*kv[2].z + kv[2].w*kv[2].w
                      + kv[3].x*kv[3].x + kv[3].y*kv[3].y + kv[3].z*kv[3].z + kv[3].w*kv[3].w;
            ssq += __shfl_xor(ssq, 1);
            ssq += __shfl_xor(ssq, 2);
            float ib = 1.f / fmaxf(sqrtf(ssq), 1e-12f);
            uint u[8];
            u[0] = packbf2(kv[0].x * ib, kv[0].y * ib); u[1] = packbf2(kv[0].z * ib, kv[0].w * ib);
            u[2] = packbf2(kv[1].x * ib, kv[1].y * ib); u[3] = packbf2(kv[1].z * ib, kv[1].w * ib);
            u[4] = packbf2(kv[2].x * ib, kv[2].y * ib); u[5] = packbf2(kv[2].z * ib, kv[2].w * ib);
            u[6] = packbf2(kv[3].x * ib, kv[3].y * ib); u[7] = packbf2(kv[3].z * ib, kv[3].w * ib);
            uint* dst = (uint*)(Bb + ssA * PST + q4A);
            *(uint4*)dst = make_uint4(u[0], u[1], u[2], u[3]);
            *(uint4*)(dst + 4) = make_uint4(u[4], u[5], u[6], u[7]);
        }
        {   // pack dt-scaled X^T (bf16 pair-packed) into Xb from regs
            float dt0 = sDt[st * 64 + 2 * ss2];
            float dt1 = sDt[st * 64 + 2 * ss2 + 1];
            float x0[8] = {xa[0].x, xa[0].y, xa[0].z, xa[0].w,
                           xa[1].x, xa[1].y, xa[1].z, xa[1].w};
            float x1[8] = {xb[0].x, xb[0].y, xb[0].z, xb[0].w,
                           xb[1].x, xb[1].y, xb[1].z, xb[1].w};
            uint* xt = (uint*)Xb;
            #pragma unroll
            for (int i = 0; i < 8; ++i)
                xt[(p0 + i) * (PST / 2) + ss2] = packbf2(x0[i] * dt0, x1[i] * dt1);
        }
        __syncthreads();

        bf16x8 xf[4][2];
        #pragma unroll
        for (int pt = 0; pt < 4; ++pt) {
            #pragma unroll
            for (int ks = 0; ks < 2; ++ks)
                xf[pt][ks] = *(const bf16x8*)(Xb + (pt * 16 + l16) * PST + ks * 32 + quad * 8);
        }

        #pragma unroll
        for (int is = 0; is < 2; ++is) {
            int strip = is ? (7 - w) : w;
            int L0 = strip * 32;
            if (L0 + 31 < st * 64) continue;

            #pragma unroll
            for (int lt = 0; lt < 2; ++lt) {
                int Lt = L0 + lt * 16;
                float cl = sCum[Lt + l16];
                int lrow = lt * 16 + l16;
                #pragma unroll
                for (int mt = 0; mt < 4; ++mt) {
                    int S0 = st * 64 + mt * 16;
                    uint* pdst = (uint*)(Pw + lrow * PST + mt * 16 + quad * 4);
                    if (S0 > Lt + 15) {
                        *(uint2*)pdst = make_uint2(0u, 0u);
                        continue;
                    }
                    f32x4 sa = (f32x4){0.f, 0.f, 0.f, 0.f};
                    bf16x8 af0 = *(const bf16x8*)(Bb + (mt * 16 + l16) * PST + quad * 8);
                    bf16x8 af1 = *(const bf16x8*)(Bb + (mt * 16 + l16) * PST + 32 + quad * 8);
                    sa = MFMA(af0, cf[is][lt][0], sa);
                    sa = MFMA(af1, cf[is][lt][1], sa);
                    float vals[4];
                    #pragma unroll
                    for (int r = 0; r < 4; ++r) {
                        int s = S0 + quad * 4 + r;
                        float v = sa[r] * __expf(cl - sCum[s]);
                        vals[r] = (Lt + l16 >= s) ? v : 0.f;
                    }
                    *(uint2*)pdst = make_uint2(packbf2(vals[0], vals[1]),
                                               packbf2(vals[2], vals[3]));
                }
            }
            #pragma unroll
            for (int lt = 0; lt < 2; ++lt) {
                int Lmax = L0 + lt * 16 + 15;
                #pragma unroll
                for (int ks = 0; ks < 2; ++ks) {
                    if (st * 64 + ks * 32 > Lmax) continue;
                    bf16x8 af = *(const bf16x8*)(Pw + (lt * 16 + l16) * PST + ks * 32 + quad * 8);
                    #pragma unroll
                    for (int pt = 0; pt < 4; ++pt)
                        acc[is][lt][pt] = MFMA(af, xf[pt][ks], acc[is][lt][pt]);
                }
            }
        }

        if (st < 3) {
            kv[0] = kvN[0]; kv[1] = kvN[1]; kv[2] = kvN[2]; kv[3] = kvN[3];
            xa[0] = xaN[0]; xa[1] = xaN[1];
            xb[0] = xbN[0]; xb[1] = xbN[1];
        }
    }

    #pragma unroll
    for (int is = 0; is < 2; ++is) {
        int strip = is ? (7 - w) : w;
        #pragma unroll
        for (int lt = 0; lt < 2; ++lt)
            #pragma unroll
            for (int pt = 0; pt < 4; ++pt)
                #pragma unroll
                for (int r = 0; r < 4; ++r) {
                    int l = strip * 32 + lt * 16 + quad * 4 + r;
                    int p = pt * 16 + l16;
                    ygb[((rowbase + l) * NH + h) * 64 + p] = f2bf(acc[is][lt][pt][r]);
                }
    }
}

// ---------------------------------------------------------------------------
// K7: fused gate + RMSNorm + per-head o_proj.
// ---------------------------------------------------------------------------
__global__ __launch_bounds__(256) void k_out(
    const short* __restrict__ ygb, const float* __restrict__ part,
    const float* __restrict__ g_b, const short* __restrict__ nwWT,
    const float* __restrict__ o_b, float* __restrict__ out)
{
    __shared__ __align__(16) short yS[16 * 1024];   // 16 rows x own head-half
    __shared__ float silS[16 * 32];
    __shared__ float scaleS[16];
    int blk = blockIdx.x;
    int half = blk & 1, rt = blk >> 1;
    int r0 = rt * 16;
    int t = threadIdx.x;
    int w = t >> 6, lane = t & 63, quad = lane >> 4, l16 = lane & 15;

    // phase 0: gates (sum g split-K partials + bias, silu) for all 32 heads
    const float* gpart = part + 4 * 131072;
    #pragma unroll
    for (int ii = 0; ii < 2; ++ii) {
        int idx = t + ii * 256;                 // (row 0..15, h 0..31)
        int rr = idx >> 5, hh = idx & 31;
        int rid = (r0 + rr) * 32 + hh;
        float g = gpart[rid] + gpart[131072 + rid] + gpart[262144 + rid]
                + gpart[393216 + rid] + g_b[hh];
        silS[idx] = g / (1.f + expf(-g));
    }
    __syncthreads();

    // phase 1: stream full rows, gated sumsq; stash own half to LDS (swizzled)
    int r = t >> 4, cl = t & 15;
    const char* yrow = (const char*)(ygb + (size_t)(r0 + r) * 2048);
    float ssq = 0.f;
    #pragma unroll
    for (int i = 0; i < 16; ++i) {
        int cb = i * 256 + cl * 16;             // byte offset 0..4095
        uint4 u = *(const uint4*)(yrow + cb);
        float s = silS[r * 32 + (cb >> 7)];
        float v0 = bf2f((ushort)(u.x & 0xFFFF)) * s, v1 = bf2f((ushort)(u.x >> 16)) * s;
        float v2 = bf2f((ushort)(u.y & 0xFFFF)) * s, v3 = bf2f((ushort)(u.y >> 16)) * s;
        float v4 = bf2f((ushort)(u.z & 0xFFFF)) * s, v5 = bf2f((ushort)(u.z >> 16)) * s;
        float v6 = bf2f((ushort)(u.w & 0xFFFF)) * s, v7 = bf2f((ushort)(u.w >> 16)) * s;
        ssq += v0*v0 + v1*v1 + v2*v2 + v3*v3 + v4*v4 + v5*v5 + v6*v6 + v7*v7;
        if ((cb >> 11) == half) {
            int cbl = cb & 2047;
            *(uint4*)((char*)yS + r * 2048 + (cbl ^ ((r & 7) << 4))) = u;
        }
    }
    ssq += __shfl_xor(ssq, 1); ssq += __shfl_xor(ssq, 2);
    ssq += __shfl_xor(ssq, 4); ssq += __shfl_xor(ssq, 8);
    if (cl == 0) scaleS[r] = rsqrtf(ssq / 2048.f + 1e-5f);
    __syncthreads();

    // phase 2: wave w handles 4 heads of its half
    #pragma unroll
    for (int hh = 0; hh < 4; ++hh) {
        int h = half * 16 + w * 4 + hh;
        int hl = h & 15;
        const short* wb = nwWT + (size_t)h * 4096;
        bf16x8 bfr[4][2];
        #pragma unroll
        for (int nt = 0; nt < 4; ++nt)
            #pragma unroll
            for (int ks = 0; ks < 2; ++ks)
                bfr[nt][ks] = *(const bf16x8*)(wb + (nt * 16 + l16) * 64 + ks * 32 + quad * 8);
        bf16x8 af[2];
        #pragma unroll
        for (int ks = 0; ks < 2; ++ks) {
            int cbl = hl * 128 + ks * 64 + quad * 16;
            af[ks] = *(const bf16x8*)((const char*)yS + l16 * 2048 + (cbl ^ ((l16 & 7) << 4)));
        }
        f32x4 acc[4];
        #pragma unroll
        for (int nt = 0; nt < 4; ++nt) acc[nt] = (f32x4){0.f, 0.f, 0.f, 0.f};
        #pragma unroll
        for (int ks = 0; ks < 2; ++ks)
            #pragma unroll
            for (int nt = 0; nt < 4; ++nt)
                acc[nt] = MFMA(af[ks], bfr[nt][ks], acc[nt]);
        #pragma unroll
        for (int nt = 0; nt < 4; ++nt) {
            float bv = o_b[h * 64 + nt * 16 + l16];
            #pragma unroll
            for (int rr = 0; rr < 4; ++rr) {
                int row = quad * 4 + rr;
                float o = acc[nt][rr] * silS[row * 32 + h] * scaleS[row] + bv;
                out[(size_t)(r0 + row) * 2048 + h * 64 + nt * 16 + l16] = o;
            }
        }
    }
}

extern "C" void kernel_launch(void* const* d_in, const int* in_sizes, int n_in,
                              void* d_out, int out_size, void* d_ws, size_t ws_size,
                              hipStream_t stream) {
    const float* hs_ab   = (const float*)d_in[0];
    const float* hs_g    = (const float*)d_in[1];
    const float* qst     = (const float*)d_in[2];
    const float* kst     = (const float*)d_in[3];
    const float* vst     = (const float*)d_in[4];
    const float* dt_w    = (const float*)d_in[5];
    const float* dt_b    = (const float*)d_in[6];
    const float* g_w     = (const float*)d_in[7];
    const float* g_b     = (const float*)d_in[8];
    const float* A_log   = (const float*)d_in[9];
    const float* dt_bias = (const float*)d_in[10];
    const float* norm_w  = (const float*)d_in[11];
    const float* o_w     = (const float*)d_in[12];
    const float* o_b     = (const float*)d_in[13];
    float* out = (float*)d_out;

    float* ws = (float*)d_ws;
    size_t off = 0;
    float* part   = ws + off; off += (size_t)2 * KSPLIT * 4096 * 32;  // 1M floats
    float* cumc   = ws + off; off += (size_t)NBCH * CHUNK;
    float* dtc    = ws + off; off += (size_t)NBCH * CHUNK;
    float* cd_ws  = ws + off; off += (size_t)NBCH;
    float* spf    = ws + off; off += (size_t)NBCH * 2 * 4096;   // region kept f32-sized
    float* Hpf    = ws + off; off += (size_t)NBCH * 4096;       // region kept f32-sized
    short* nwWT   = (short*)(ws + off); off += (size_t)NH * 64 * 64 / 2;  // 131072 shorts

    short* sp  = (short*)spf;   // bf16 states (uses half the region)
    short* Hp  = (short*)Hpf;   // bf16 H_prev (uses half the region)
    short* ygb = (short*)spf;   // aliases sp region (sp fully consumed by k_scan)

    k_proj<<<2 * KSPLIT * (BATCH * SEQ / 32) + NH, 256, 0, stream>>>(
        hs_ab, hs_g, dt_w, g_w, o_w, norm_w, part, nwWT);
    k_states<<<NBCH * 2, 256, 0, stream>>>(part, dt_b, dt_bias, A_log,
                                           kst, vst, cumc, dtc, cd_ws, sp);
    k_scan<<<BATCH * NH * 4096 / 256, 256, 0, stream>>>(sp, cd_ws, Hp);
    k_intra<<<NBCH, 256, 0, stream>>>(qst, kst, vst, cumc, dtc, Hp, ygb);
    k_out<<<2 * (BATCH * SEQ / 16), 256, 0, stream>>>(ygb, part, g_b, nwWT, o_b, out);
}

// Round 12
// 257.215 us; speedup vs baseline: 1.0874x; 1.0019x over previous
//
#include <hip/hip_runtime.h>
#include <math.h>

#define BATCH 2
#define SEQ   2048
#define NH    32
#define HID   2048
#define CHUNK 256
#define NCH   8
#define NBCH  (BATCH*NCH*NH)   // 512
#define PST   72               // padded bf16 LDS leading dim (b128-alignable)
#define BK    256
#define APST  264              // BK+8 shorts; row stride 528 B = 33*16 (b128-aligned)
#define KSPLIT 4
#define KSEG  (HID / KSPLIT)   // 512

typedef __attribute__((ext_vector_type(4))) float f32x4;
typedef __attribute__((ext_vector_type(8))) short bf16x8;
typedef unsigned int uint;
typedef unsigned short ushort;

__device__ __forceinline__ float softplusf(float x) {
    return x > 20.f ? x : log1pf(expf(x));
}

// HW packed f32->bf16 RNE (1 VALU op; bit-identical to manual round, R9).
__device__ __forceinline__ uint packbf2(float lo, float hi) {
    uint r;
    asm("v_cvt_pk_bf16_f32 %0, %1, %2" : "=v"(r) : "v"(lo), "v"(hi));
    return r;
}
__device__ __forceinline__ short f2bf(float f) {
    return (short)packbf2(f, 0.f);
}
__device__ __forceinline__ float bf2f(ushort s) {
    union { uint u; float f; } v; v.u = ((uint)s) << 16; return v.f;
}

__device__ __forceinline__ bf16x8 load_cvt8(const float* p, float scale) {
    float4 a = *(const float4*)p;
    float4 b = *(const float4*)(p + 4);
    union { bf16x8 v; uint u[4]; } r;
    r.u[0] = packbf2(a.x * scale, a.y * scale);
    r.u[1] = packbf2(a.z * scale, a.w * scale);
    r.u[2] = packbf2(b.x * scale, b.y * scale);
    r.u[3] = packbf2(b.z * scale, b.w * scale);
    return r.v;
}

__device__ __forceinline__ bf16x8 cvt8(float4 a, float4 b, float s) {
    union { bf16x8 v; uint u[4]; } r;
    r.u[0] = packbf2(a.x * s, a.y * s);
    r.u[1] = packbf2(a.z * s, a.w * s);
    r.u[2] = packbf2(b.x * s, b.y * s);
    r.u[3] = packbf2(b.z * s, b.w * s);
    return r.v;
}

#define MFMA(a,b,c) __builtin_amdgcn_mfma_f32_16x16x32_bf16((a),(b),(c),0,0,0)

// ---------------------------------------------------------------------------
// K1: dt/g projections as bf16 MFMA GEMM (split-K by 4), plus 32 trailing
// blocks that build nwWT[h][q][p] = bf16(o_w[h][p][q] * norm_w[h*64+p]).
// ---------------------------------------------------------------------------
__global__ __launch_bounds__(256) void k_proj(
    const float* __restrict__ hs_ab, const float* __restrict__ hs_g,
    const float* __restrict__ dt_w, const float* __restrict__ g_w,
    const float* __restrict__ o_w,  const float* __restrict__ norm_w,
    float* __restrict__ part, short* __restrict__ nwWT)
{
    __shared__ __align__(16) short As[32 * APST];
    __shared__ __align__(16) short Bs[32 * APST];
    int blk = blockIdx.x;
    int t = threadIdx.x;

    if (blk >= 2 * KSPLIT * 128) {
        // --- weight prep: transpose o_w per head, fold norm_w, cast bf16 ---
        int h = blk - 2 * KSPLIT * 128;
        float* tile = (float*)As;   // 64x64 f32 = 16 KB
        {
            int p = t >> 2, q0 = (t & 3) * 16;
            const float* wp = o_w + (size_t)h * 4096 + p * 64 + q0;
            #pragma unroll
            for (int i = 0; i < 4; ++i)
                *(float4*)(tile + p * 64 + q0 + i * 4) = *(const float4*)(wp + i * 4);
        }
        __syncthreads();
        int q = t >> 2, p0 = (t & 3) * 16;
        uint us[8];
        #pragma unroll
        for (int j = 0; j < 8; ++j) {
            float lo = tile[(p0 + 2*j    ) * 64 + q] * norm_w[h * 64 + p0 + 2*j];
            float hi = tile[(p0 + 2*j + 1) * 64 + q] * norm_w[h * 64 + p0 + 2*j + 1];
            us[j] = packbf2(lo, hi);
        }
        uint* dst = (uint*)(nwWT + (size_t)h * 4096 + q * 64 + p0);
        *(uint4*)dst       = make_uint4(us[0], us[1], us[2], us[3]);
        *(uint4*)(dst + 4) = make_uint4(us[4], us[5], us[6], us[7]);
        return;
    }

    int ksp = blk >> 8;          // 0..3 : K segment
    int rem = blk & 255;
    int which = rem >> 7;        // 0..1 : ab vs g
    int rt = rem & 127;          // 0..127 : 32-row tile
    int r0 = rt * 32;
    const float* Am = which ? hs_g : hs_ab;
    const float* W  = which ? g_w  : dt_w;
    int w = t >> 6, lane = t & 63, quad = lane >> 4, l16 = lane & 15;
    int mh = w & 1, nh = w >> 1;

    f32x4 acc = (f32x4){0.f, 0.f, 0.f, 0.f};

    for (int kc = ksp * KSEG; kc < ksp * KSEG + KSEG; kc += BK) {
        __syncthreads();
        {   // stage A: 32 rows x BK cols, bf16-packed
            int row = t >> 3, k0 = (t & 7) * 32;
            const float* src = Am + (size_t)(r0 + row) * HID + kc + k0;
            uint* dst = (uint*)(As + row * APST + k0);
            #pragma unroll
            for (int i = 0; i < 4; ++i) {
                float4 a = *(const float4*)(src + i * 8);
                float4 b = *(const float4*)(src + i * 8 + 4);
                dst[i*4+0] = packbf2(a.x, a.y); dst[i*4+1] = packbf2(a.z, a.w);
                dst[i*4+2] = packbf2(b.x, b.y); dst[i*4+3] = packbf2(b.z, b.w);
            }
        }
        if (t < 128) {   // stage W transposed: Bs[n][k] = W[kc+k][n], pair-packed
            int k2 = t * 2;
            const float* w0 = W + (size_t)(kc + k2) * NH;
            const float* w1 = w0 + NH;
            #pragma unroll
            for (int n = 0; n < 32; n += 4) {
                float4 a = *(const float4*)(w0 + n);
                float4 b = *(const float4*)(w1 + n);
                *((uint*)(Bs + (n+0) * APST + k2)) = packbf2(a.x, b.x);
                *((uint*)(Bs + (n+1) * APST + k2)) = packbf2(a.y, b.y);
                *((uint*)(Bs + (n+2) * APST + k2)) = packbf2(a.z, b.z);
                *((uint*)(Bs + (n+3) * APST + k2)) = packbf2(a.w, b.w);
            }
        }
        __syncthreads();
        #pragma unroll
        for (int ks = 0; ks < BK / 32; ++ks) {
            bf16x8 af = *(const bf16x8*)(As + (mh*16 + l16) * APST + ks*32 + quad*8);
            bf16x8 bf = *(const bf16x8*)(Bs + (nh*16 + l16) * APST + ks*32 + quad*8);
            acc = MFMA(af, bf, acc);
        }
    }

    int n = nh * 16 + l16;
    int Rb = r0 + mh * 16 + quad * 4;
    float* pd = part + ((size_t)(which * KSPLIT + ksp) * 4096 + Rb) * 32 + n;
    #pragma unroll
    for (int r = 0; r < 4; ++r)
        pd[r * 32] = acc[r];
}

// ---------------------------------------------------------------------------
// K4: chunk-state GEMM via MFMA with k_cumsum absorbed (R10); bf16 states
// (R11).
// ---------------------------------------------------------------------------
__global__ __launch_bounds__(256) void k_states(
    const float* __restrict__ part, const float* __restrict__ dt_b,
    const float* __restrict__ dt_bias, const float* __restrict__ A_log,
    const float* __restrict__ kst, const float* __restrict__ vst,
    float* __restrict__ cumc, float* __restrict__ dtc, float* __restrict__ cd,
    short* __restrict__ sp)
{
    __shared__ __align__(16) short kT[64 * PST];    // khat^T  [n][s]
    __shared__ __align__(16) short xwT[64 * PST];   // (x*wv)^T [p][s]
    __shared__ float wsum[4];
    __shared__ float sWv[256];

    int blk = blockIdx.x;
    int half = blk & 1, bch = blk >> 1;
    int h = bch & 31, c = (bch >> 5) & 7, b = bch >> 8;
    int t = threadIdx.x;
    int w = t >> 6, lane = t & 63;
    int quad = lane >> 4, l16 = lane & 15;
    size_t rowbase = (size_t)b * SEQ + c * CHUNK;

    // ---- absorbed cumsum: full-chunk scan (row = t) ----
    {
        int rid = (b * SEQ + c * CHUNK + t) * 32 + h;
        float s = part[rid] + part[131072 + rid] + part[262144 + rid] + part[393216 + rid];
        float dt_l = softplusf(s + dt_b[h] + dt_bias[h]);
        float A = -expf(A_log[h]);
        float v = dt_l * A;
        #pragma unroll
        for (int off = 1; off < 64; off <<= 1) {
            float u = __shfl_up(v, off);
            if (lane >= off) v += u;
        }
        if (lane == 63) wsum[w] = v;
        __syncthreads();
        float pre = 0.f;
        #pragma unroll
        for (int i = 0; i < 3; ++i)
            if (i < w) pre += wsum[i];
        float cum = v + pre;
        float tot = wsum[0] + wsum[1] + wsum[2] + wsum[3];
        sWv[t] = expf(tot - cum) * dt_l;
        if ((t >> 7) == half) {      // each half-block writes its own rows once
            size_t o = (size_t)bch * CHUNK + t;
            cumc[o] = cum;
            dtc[o] = dt_l;
        }
        if (half == 1 && t == 255) cd[bch] = expf(tot);
    }
    __syncthreads();

    int rowl = t >> 2;             // 0..63 row within tile
    int q4 = (t & 3) * 16;         // 16-col group

    f32x4 acc[4];
    #pragma unroll
    for (int nt = 0; nt < 4; ++nt) acc[nt] = (f32x4){0.f, 0.f, 0.f, 0.f};

    for (int tt = 0; tt < 2; ++tt) {
        int r0 = half * 128 + tt * 64;
        size_t grow = (rowbase + r0 + rowl) * NH + h;
        {   // stage khat^T: 16 cols of one k-row; invB via 4-lane reduce
            const float4* kp = (const float4*)(kst + grow * 64 + q4);
            float4 k0 = kp[0], k1 = kp[1], k2 = kp[2], k3 = kp[3];
            float ssq = k0.x*k0.x + k0.y*k0.y + k0.z*k0.z + k0.w*k0.w
                      + k1.x*k1.x + k1.y*k1.y + k1.z*k1.z + k1.w*k1.w
                      + k2.x*k2.x + k2.y*k2.y + k2.z*k2.z + k2.w*k2.w
                      + k3.x*k3.x + k3.y*k3.y + k3.z*k3.z + k3.w*k3.w;
            ssq += __shfl_xor(ssq, 1);
            ssq += __shfl_xor(ssq, 2);
            float ib = 1.f / fmaxf(sqrtf(ssq), 1e-12f);
            uint u0 = packbf2(k0.x*ib, k0.y*ib), u1 = packbf2(k0.z*ib, k0.w*ib);
            uint u2 = packbf2(k1.x*ib, k1.y*ib), u3 = packbf2(k1.z*ib, k1.w*ib);
            uint u4 = packbf2(k2.x*ib, k2.y*ib), u5 = packbf2(k2.z*ib, k2.w*ib);
            uint u6 = packbf2(k3.x*ib, k3.y*ib), u7 = packbf2(k3.z*ib, k3.w*ib);
            kT[(q4+ 0)*PST + rowl] = (short)u0; kT[(q4+ 1)*PST + rowl] = (short)(u0>>16);
            kT[(q4+ 2)*PST + rowl] = (short)u1; kT[(q4+ 3)*PST + rowl] = (short)(u1>>16);
            kT[(q4+ 4)*PST + rowl] = (short)u2; kT[(q4+ 5)*PST + rowl] = (short)(u2>>16);
            kT[(q4+ 6)*PST + rowl] = (short)u3; kT[(q4+ 7)*PST + rowl] = (short)(u3>>16);
            kT[(q4+ 8)*PST + rowl] = (short)u4; kT[(q4+ 9)*PST + rowl] = (short)(u4>>16);
            kT[(q4+10)*PST + rowl] = (short)u5; kT[(q4+11)*PST + rowl] = (short)(u5>>16);
            kT[(q4+12)*PST + rowl] = (short)u6; kT[(q4+13)*PST + rowl] = (short)(u6>>16);
            kT[(q4+14)*PST + rowl] = (short)u7; kT[(q4+15)*PST + rowl] = (short)(u7>>16);
        }
        {   // stage (x*wv)^T
            const float4* xp = (const float4*)(vst + grow * 64 + q4);
            float4 x0 = xp[0], x1 = xp[1], x2 = xp[2], x3 = xp[3];
            float wv = sWv[r0 + rowl];
            uint u0 = packbf2(x0.x*wv, x0.y*wv), u1 = packbf2(x0.z*wv, x0.w*wv);
            uint u2 = packbf2(x1.x*wv, x1.y*wv), u3 = packbf2(x1.z*wv, x1.w*wv);
            uint u4 = packbf2(x2.x*wv, x2.y*wv), u5 = packbf2(x2.z*wv, x2.w*wv);
            uint u6 = packbf2(x3.x*wv, x3.y*wv), u7 = packbf2(x3.z*wv, x3.w*wv);
            xwT[(q4+ 0)*PST + rowl] = (short)u0; xwT[(q4+ 1)*PST + rowl] = (short)(u0>>16);
            xwT[(q4+ 2)*PST + rowl] = (short)u1; xwT[(q4+ 3)*PST + rowl] = (short)(u1>>16);
            xwT[(q4+ 4)*PST + rowl] = (short)u2; xwT[(q4+ 5)*PST + rowl] = (short)(u2>>16);
            xwT[(q4+ 6)*PST + rowl] = (short)u3; xwT[(q4+ 7)*PST + rowl] = (short)(u3>>16);
            xwT[(q4+ 8)*PST + rowl] = (short)u4; xwT[(q4+ 9)*PST + rowl] = (short)(u4>>16);
            xwT[(q4+10)*PST + rowl] = (short)u5; xwT[(q4+11)*PST + rowl] = (short)(u5>>16);
            xwT[(q4+12)*PST + rowl] = (short)u6; xwT[(q4+13)*PST + rowl] = (short)(u6>>16);
            xwT[(q4+14)*PST + rowl] = (short)u7; xwT[(q4+15)*PST + rowl] = (short)(u7>>16);
        }
        __syncthreads();

        #pragma unroll
        for (int ks = 0; ks < 2; ++ks) {
            bf16x8 a = *(const bf16x8*)(xwT + (w*16 + l16)*PST + ks*32 + quad*8);
            #pragma unroll
            for (int nt = 0; nt < 4; ++nt) {
                bf16x8 bb = *(const bf16x8*)(kT + (nt*16 + l16)*PST + ks*32 + quad*8);
                acc[nt] = MFMA(a, bb, acc[nt]);
            }
        }
        __syncthreads();
    }

    size_t obase = (size_t)blk * 4096;
    #pragma unroll
    for (int nt = 0; nt < 4; ++nt)
        #pragma unroll
        for (int r = 0; r < 4; ++r)
            sp[obase + (w*16 + quad*4 + r) * 64 + nt*16 + l16] = f2bf(acc[nt][r]);
}

// ---------------------------------------------------------------------------
// K5: inter-chunk scan (bf16 in/out; f32 carry in-register).
// ---------------------------------------------------------------------------
__global__ __launch_bounds__(256) void k_scan(
    const short* __restrict__ sp, const float* __restrict__ cd,
    short* __restrict__ Hp)
{
    size_t id = (size_t)blockIdx.x * 256 + threadIdx.x;
    size_t bh = id >> 12, pn = id & 4095;
    size_t b = bh >> 5, h = bh & 31;
    float carry = 0.f;
    for (int c = 0; c < NCH; ++c) {
        size_t bch = (b * NCH + c) * NH + h;
        float st = bf2f((ushort)sp[(bch * 2) * 4096 + pn])
                 + bf2f((ushort)sp[(bch * 2 + 1) * 4096 + pn]);
        Hp[bch * 4096 + pn] = f2bf(carry);
        carry = cd[bch] * carry + st;
    }
}

// ---------------------------------------------------------------------------
// K6: MFMA intra-chunk + H_prev (R9 structure — best of 6 variants; bf16 Hp).
// ---------------------------------------------------------------------------
__global__ __launch_bounds__(256, 2) void k_intra(
    const float* __restrict__ qst, const float* __restrict__ kst,
    const float* __restrict__ vst,
    const float* __restrict__ cumc, const float* __restrict__ dtc,
    const short* __restrict__ Hp,
    short* __restrict__ ygb)
{
    __shared__ __align__(16) short B_s[2][64 * PST];
    __shared__ __align__(16) short XT_s[2][64 * PST];
    __shared__ __align__(16) short P_s[4 * 32 * PST];
    __shared__ float sCum[256];
    __shared__ float sDt[256];

    int bch = blockIdx.x;
    int h = bch & 31, c = (bch >> 5) & 7, b = bch >> 8;
    int t = threadIdx.x;
    int w = t >> 6, lane = t & 63;
    int quad = lane >> 4, l16 = lane & 15;
    size_t rowbase = (size_t)b * SEQ + c * CHUNK;

    sCum[t] = cumc[(size_t)bch * CHUNK + t];
    sDt[t]  = dtc[(size_t)bch * CHUNK + t];

    // staging thread mapping (constant across st)
    int ssA = t >> 2, q4A = (t & 3) * 16;      // B_s: row ssA, 16-col group
    int ss2 = t & 31, p0 = (t >> 5) * 8;       // XT: rows 2*ss2(+1), 8 p's

    // prefetch k/v for st=0 (flies under the Q/Hp prologue)
    float4 kv[4], xa[2], xb[2];
    {
        size_t gK = (rowbase + ssA) * NH + h;
        const float4* kp = (const float4*)(kst + gK * 64 + q4A);
        kv[0] = kp[0]; kv[1] = kp[1]; kv[2] = kp[2]; kv[3] = kp[3];
        size_t g0 = (rowbase + 2 * ss2) * NH + h;
        const float* vp0 = vst + g0 * 64 + p0;
        const float* vp1 = vst + (g0 + NH) * 64 + p0;
        xa[0] = *(const float4*)vp0; xa[1] = *(const float4*)(vp0 + 4);
        xb[0] = *(const float4*)vp1; xb[1] = *(const float4*)(vp1 + 4);
    }

    bf16x8 cf[2][2][2];
    #pragma unroll
    for (int is = 0; is < 2; ++is) {
        int strip = is ? (7 - w) : w;
        #pragma unroll
        for (int lt = 0; lt < 2; ++lt) {
            int l = strip * 32 + lt * 16 + l16;
            size_t grow = (rowbase + l) * NH + h;
            const float* qp = qst + grow * 64 + quad * 8;
            float4 a  = *(const float4*)qp;
            float4 bq = *(const float4*)(qp + 4);
            float4 c2 = *(const float4*)(qp + 32);
            float4 d  = *(const float4*)(qp + 36);
            float ssq = a.x*a.x + a.y*a.y + a.z*a.z + a.w*a.w
                      + bq.x*bq.x + bq.y*bq.y + bq.z*bq.z + bq.w*bq.w
                      + c2.x*c2.x + c2.y*c2.y + c2.z*c2.z + c2.w*c2.w
                      + d.x*d.x + d.y*d.y + d.z*d.z + d.w*d.w;
            ssq += __shfl_xor(ssq, 16);
            ssq += __shfl_xor(ssq, 32);
            float ic = 1.f / fmaxf(sqrtf(ssq), 1e-12f);
            cf[is][lt][0] = cvt8(a, bq, ic);
            cf[is][lt][1] = cvt8(c2, d, ic);
        }
    }

    f32x4 acc[2][2][4];
    #pragma unroll
    for (int is = 0; is < 2; ++is)
        #pragma unroll
        for (int lt = 0; lt < 2; ++lt)
            #pragma unroll
            for (int pt = 0; pt < 4; ++pt)
                acc[is][lt][pt] = (f32x4){0.f, 0.f, 0.f, 0.f};

    {
        bf16x8 hf[4][2];
        #pragma unroll
        for (int pt = 0; pt < 4; ++pt) {
            const short* hp = Hp + (size_t)bch * 4096 + (pt * 16 + l16) * 64 + quad * 8;
            hf[pt][0] = *(const bf16x8*)hp;
            hf[pt][1] = *(const bf16x8*)(hp + 32);
        }
        #pragma unroll
        for (int is = 0; is < 2; ++is)
            #pragma unroll
            for (int lt = 0; lt < 2; ++lt)
                #pragma unroll
                for (int pt = 0; pt < 4; ++pt) {
                    acc[is][lt][pt] = MFMA(cf[is][lt][0], hf[pt][0], acc[is][lt][pt]);
                    acc[is][lt][pt] = MFMA(cf[is][lt][1], hf[pt][1], acc[is][lt][pt]);
                }
    }
    __syncthreads();   // sCum/sDt now visible to all waves
    #pragma unroll
    for (int is = 0; is < 2; ++is) {
        int strip = is ? (7 - w) : w;
        #pragma unroll
        for (int lt = 0; lt < 2; ++lt) {
            float e[4];
            #pragma unroll
            for (int r = 0; r < 4; ++r)
                e[r] = __expf(sCum[strip * 32 + lt * 16 + quad * 4 + r]);
            #pragma unroll
            for (int pt = 0; pt < 4; ++pt)
                #pragma unroll
                for (int r = 0; r < 4; ++r)
                    acc[is][lt][pt][r] *= e[r];
        }
    }

    short* Pw = P_s + w * 32 * PST;

    #pragma unroll
    for (int st = 0; st < 4; ++st) {
        // issue next-tile global loads first (hide under pack+barrier+compute)
        float4 kvN[4], xaN[2], xbN[2];
        if (st < 3) {
            size_t gK = (rowbase + (st + 1) * 64 + ssA) * NH + h;
            const float4* kp = (const float4*)(kst + gK * 64 + q4A);
            kvN[0] = kp[0]; kvN[1] = kp[1]; kvN[2] = kp[2]; kvN[3] = kp[3];
            size_t g0 = (rowbase + (st + 1) * 64 + 2 * ss2) * NH + h;
            const float* vp0 = vst + g0 * 64 + p0;
            const float* vp1 = vst + (g0 + NH) * 64 + p0;
            xaN[0] = *(const float4*)vp0; xaN[1] = *(const float4*)(vp0 + 4);
            xbN[0] = *(const float4*)vp1; xbN[1] = *(const float4*)(vp1 + 4);
        }

        short* Bb = B_s[st & 1];
        short* Xb = XT_s[st & 1];
        {   // pack K-hat (bf16) into Bb from regs
            float ssq = kv[0].x*kv[0].x + kv[0].y*kv[0].y + kv[0].z*kv[0].z + kv[0].w*kv[0].w
                      + kv[1].x*kv[1].x + kv[1].y*kv[1].y + kv[1].z*kv[1].z + kv[1].w*kv[1].w
                      + kv[2].x*kv[2].x + kv[2].y*kv[2].y + kv[2].z*kv[2].z + kv[2].w*kv[2].w
                      + kv[3].x*kv[3].x + kv[3].y*kv[3].y + kv[3].z*kv[3].z + kv[3].w*kv[3].w;
            ssq += __shfl_xor(ssq, 1);
            ssq += __shfl_xor(ssq, 2);
            float ib = 1.f / fmaxf(sqrtf(ssq), 1e-12f);
            uint u[8];
            u[0] = packbf2(kv[0].x * ib, kv[0].y * ib); u[1] = packbf2(kv[0].z * ib, kv[0].w * ib);
            u[2] = packbf2(kv[1].x * ib, kv[1].y * ib); u[3] = packbf2(kv[1].z * ib, kv[1].w * ib);
            u[4] = packbf2(kv[2].x * ib, kv[2].y * ib); u[5] = packbf2(kv[2].z * ib, kv[2].w * ib);
            u[6] = packbf2(kv[3].x * ib, kv[3].y * ib); u[7] = packbf2(kv[3].z * ib, kv[3].w * ib);
            uint* dst = (uint*)(Bb + ssA * PST + q4A);
            *(uint4*)dst = make_uint4(u[0], u[1], u[2], u[3]);
            *(uint4*)(dst + 4) = make_uint4(u[4], u[5], u[6], u[7]);
        }
        {   // pack dt-scaled X^T (bf16 pair-packed) into Xb from regs
            float dt0 = sDt[st * 64 + 2 * ss2];
            float dt1 = sDt[st * 64 + 2 * ss2 + 1];
            float x0[8] = {xa[0].x, xa[0].y, xa[0].z, xa[0].w,
                           xa[1].x, xa[1].y, xa[1].z, xa[1].w};
            float x1[8] = {xb[0].x, xb[0].y, xb[0].z, xb[0].w,
                           xb[1].x, xb[1].y, xb[1].z, xb[1].w};
            uint* xt = (uint*)Xb;
            #pragma unroll
            for (int i = 0; i < 8; ++i)
                xt[(p0 + i) * (PST / 2) + ss2] = packbf2(x0[i] * dt0, x1[i] * dt1);
        }
        __syncthreads();

        bf16x8 xf[4][2];
        #pragma unroll
        for (int pt = 0; pt < 4; ++pt) {
            #pragma unroll
            for (int ks = 0; ks < 2; ++ks)
                xf[pt][ks] = *(const bf16x8*)(Xb + (pt * 16 + l16) * PST + ks * 32 + quad * 8);
        }

        #pragma unroll
        for (int is = 0; is < 2; ++is) {
            int strip = is ? (7 - w) : w;
            int L0 = strip * 32;
            if (L0 + 31 < st * 64) continue;

            #pragma unroll
            for (int lt = 0; lt < 2; ++lt) {
                int Lt = L0 + lt * 16;
                float cl = sCum[Lt + l16];
                int lrow = lt * 16 + l16;
                #pragma unroll
                for (int mt = 0; mt < 4; ++mt) {
                    int S0 = st * 64 + mt * 16;
                    uint* pdst = (uint*)(Pw + lrow * PST + mt * 16 + quad * 4);
                    if (S0 > Lt + 15) {
                        *(uint2*)pdst = make_uint2(0u, 0u);
                        continue;
                    }
                    f32x4 sa = (f32x4){0.f, 0.f, 0.f, 0.f};
                    bf16x8 af0 = *(const bf16x8*)(Bb + (mt * 16 + l16) * PST + quad * 8);
                    bf16x8 af1 = *(const bf16x8*)(Bb + (mt * 16 + l16) * PST + 32 + quad * 8);
                    sa = MFMA(af0, cf[is][lt][0], sa);
                    sa = MFMA(af1, cf[is][lt][1], sa);
                    float vals[4];
                    #pragma unroll
                    for (int r = 0; r < 4; ++r) {
                        int s = S0 + quad * 4 + r;
                        float v = sa[r] * __expf(cl - sCum[s]);
                        vals[r] = (Lt + l16 >= s) ? v : 0.f;
                    }
                    *(uint2*)pdst = make_uint2(packbf2(vals[0], vals[1]),
                                               packbf2(vals[2], vals[3]));
                }
            }
            #pragma unroll
            for (int lt = 0; lt < 2; ++lt) {
                int Lmax = L0 + lt * 16 + 15;
                #pragma unroll
                for (int ks = 0; ks < 2; ++ks) {
                    if (st * 64 + ks * 32 > Lmax) continue;
                    bf16x8 af = *(const bf16x8*)(Pw + (lt * 16 + l16) * PST + ks * 32 + quad * 8);
                    #pragma unroll
                    for (int pt = 0; pt < 4; ++pt)
                        acc[is][lt][pt] = MFMA(af, xf[pt][ks], acc[is][lt][pt]);
                }
            }
        }

        if (st < 3) {
            kv[0] = kvN[0]; kv[1] = kvN[1]; kv[2] = kvN[2]; kv[3] = kvN[3];
            xa[0] = xaN[0]; xa[1] = xaN[1];
            xb[0] = xbN[0]; xb[1] = xbN[1];
        }
    }

    #pragma unroll
    for (int is = 0; is < 2; ++is) {
        int strip = is ? (7 - w) : w;
        #pragma unroll
        for (int lt = 0; lt < 2; ++lt)
            #pragma unroll
            for (int pt = 0; pt < 4; ++pt)
                #pragma unroll
                for (int r = 0; r < 4; ++r) {
                    int l = strip * 32 + lt * 16 + quad * 4 + r;
                    int p = pt * 16 + l16;
                    ygb[((rowbase + l) * NH + h) * 64 + p] = f2bf(acc[is][lt][pt][r]);
                }
    }
}

// ---------------------------------------------------------------------------
// K7: fused gate + RMSNorm + per-head o_proj. R12: one block per 16 rows,
// ALL 32 heads (was 2 half-blocks each streaming the full row for the
// sumsq -> ygb read twice). Grid 512 -> 256; yS = full rows (64 KB LDS,
// gfx950 allows 160 KB/WG); each wave's MFMA phase covers 8 heads.
// Saves 16.8 MB of duplicated HBM read.
// ---------------------------------------------------------------------------
__global__ __launch_bounds__(256) void k_out(
    const short* __restrict__ ygb, const float* __restrict__ part,
    const float* __restrict__ g_b, const short* __restrict__ nwWT,
    const float* __restrict__ o_b, float* __restrict__ out)
{
    __shared__ __align__(16) short yS[16 * 2048];   // 16 full rows, 64 KB
    __shared__ float silS[16 * 32];
    __shared__ float scaleS[16];
    int blk = blockIdx.x;          // 0..255
    int r0 = blk * 16;
    int t = threadIdx.x;
    int w = t >> 6, lane = t & 63, quad = lane >> 4, l16 = lane & 15;

    // phase 0: gates (sum g split-K partials + bias, silu) for all 32 heads
    const float* gpart = part + 4 * 131072;
    #pragma unroll
    for (int ii = 0; ii < 2; ++ii) {
        int idx = t + ii * 256;                 // (row 0..15, h 0..31)
        int rr = idx >> 5, hh = idx & 31;
        int rid = (r0 + rr) * 32 + hh;
        float g = gpart[rid] + gpart[131072 + rid] + gpart[262144 + rid]
                + gpart[393216 + rid] + g_b[hh];
        silS[idx] = g / (1.f + expf(-g));
    }
    __syncthreads();

    // phase 1: stream each row ONCE, gated sumsq; full-row stash (swizzled)
    int r = t >> 4, cl = t & 15;
    const char* yrow = (const char*)(ygb + (size_t)(r0 + r) * 2048);
    float ssq = 0.f;
    #pragma unroll
    for (int i = 0; i < 16; ++i) {
        int cb = i * 256 + cl * 16;             // byte offset 0..4095
        uint4 u = *(const uint4*)(yrow + cb);
        float s = silS[r * 32 + (cb >> 7)];
        float v0 = bf2f((ushort)(u.x & 0xFFFF)) * s, v1 = bf2f((ushort)(u.x >> 16)) * s;
        float v2 = bf2f((ushort)(u.y & 0xFFFF)) * s, v3 = bf2f((ushort)(u.y >> 16)) * s;
        float v4 = bf2f((ushort)(u.z & 0xFFFF)) * s, v5 = bf2f((ushort)(u.z >> 16)) * s;
        float v6 = bf2f((ushort)(u.w & 0xFFFF)) * s, v7 = bf2f((ushort)(u.w >> 16)) * s;
        ssq += v0*v0 + v1*v1 + v2*v2 + v3*v3 + v4*v4 + v5*v5 + v6*v6 + v7*v7;
        *(uint4*)((char*)yS + r * 4096 + (cb ^ ((r & 7) << 4))) = u;
    }
    ssq += __shfl_xor(ssq, 1); ssq += __shfl_xor(ssq, 2);
    ssq += __shfl_xor(ssq, 4); ssq += __shfl_xor(ssq, 8);
    if (cl == 0) scaleS[r] = rsqrtf(ssq / 2048.f + 1e-5f);
    __syncthreads();

    // phase 2: wave w handles 8 heads
    #pragma unroll
    for (int hh = 0; hh < 8; ++hh) {
        int h = w * 8 + hh;
        const short* wb = nwWT + (size_t)h * 4096;
        bf16x8 bfr[4][2];
        #pragma unroll
        for (int nt = 0; nt < 4; ++nt)
            #pragma unroll
            for (int ks = 0; ks < 2; ++ks)
                bfr[nt][ks] = *(const bf16x8*)(wb + (nt * 16 + l16) * 64 + ks * 32 + quad * 8);
        bf16x8 af[2];
        #pragma unroll
        for (int ks = 0; ks < 2; ++ks) {
            int cbl = h * 128 + ks * 64 + quad * 16;
            af[ks] = *(const bf16x8*)((const char*)yS + l16 * 4096 + (cbl ^ ((l16 & 7) << 4)));
        }
        f32x4 acc[4];
        #pragma unroll
        for (int nt = 0; nt < 4; ++nt) acc[nt] = (f32x4){0.f, 0.f, 0.f, 0.f};
        #pragma unroll
        for (int ks = 0; ks < 2; ++ks)
            #pragma unroll
            for (int nt = 0; nt < 4; ++nt)
                acc[nt] = MFMA(af[ks], bfr[nt][ks], acc[nt]);
        #pragma unroll
        for (int nt = 0; nt < 4; ++nt) {
            float bv = o_b[h * 64 + nt * 16 + l16];
            #pragma unroll
            for (int rr = 0; rr < 4; ++rr) {
                int row = quad * 4 + rr;
                float o = acc[nt][rr] * silS[row * 32 + h] * scaleS[row] + bv;
                out[(size_t)(r0 + row) * 2048 + h * 64 + nt * 16 + l16] = o;
            }
        }
    }
}

extern "C" void kernel_launch(void* const* d_in, const int* in_sizes, int n_in,
                              void* d_out, int out_size, void* d_ws, size_t ws_size,
                              hipStream_t stream) {
    const float* hs_ab   = (const float*)d_in[0];
    const float* hs_g    = (const float*)d_in[1];
    const float* qst     = (const float*)d_in[2];
    const float* kst     = (const float*)d_in[3];
    const float* vst     = (const float*)d_in[4];
    const float* dt_w    = (const float*)d_in[5];
    const float* dt_b    = (const float*)d_in[6];
    const float* g_w     = (const float*)d_in[7];
    const float* g_b     = (const float*)d_in[8];
    const float* A_log   = (const float*)d_in[9];
    const float* dt_bias = (const float*)d_in[10];
    const float* norm_w  = (const float*)d_in[11];
    const float* o_w     = (const float*)d_in[12];
    const float* o_b     = (const float*)d_in[13];
    float* out = (float*)d_out;

    float* ws = (float*)d_ws;
    size_t off = 0;
    float* part   = ws + off; off += (size_t)2 * KSPLIT * 4096 * 32;  // 1M floats
    float* cumc   = ws + off; off += (size_t)NBCH * CHUNK;
    float* dtc    = ws + off; off += (size_t)NBCH * CHUNK;
    float* cd_ws  = ws + off; off += (size_t)NBCH;
    float* spf    = ws + off; off += (size_t)NBCH * 2 * 4096;   // region kept f32-sized
    float* Hpf    = ws + off; off += (size_t)NBCH * 4096;       // region kept f32-sized
    short* nwWT   = (short*)(ws + off); off += (size_t)NH * 64 * 64 / 2;  // 131072 shorts

    short* sp  = (short*)spf;   // bf16 states (uses half the region)
    short* Hp  = (short*)Hpf;   // bf16 H_prev (uses half the region)
    short* ygb = (short*)spf;   // aliases sp region (sp fully consumed by k_scan)

    k_proj<<<2 * KSPLIT * (BATCH * SEQ / 32) + NH, 256, 0, stream>>>(
        hs_ab, hs_g, dt_w, g_w, o_w, norm_w, part, nwWT);
    k_states<<<NBCH * 2, 256, 0, stream>>>(part, dt_b, dt_bias, A_log,
                                           kst, vst, cumc, dtc, cd_ws, sp);
    k_scan<<<BATCH * NH * 4096 / 256, 256, 0, stream>>>(sp, cd_ws, Hp);
    k_intra<<<NBCH, 256, 0, stream>>>(qst, kst, vst, cumc, dtc, Hp, ygb);
    k_out<<<BATCH * SEQ / 16, 256, 0, stream>>>(ygb, part, g_b, nwWT, o_b, out);
}